// Round 1
// baseline (1402.493 us; speedup 1.0000x reference)
//
#include <hip/hip_runtime.h>

#define N_NODES 100000
#define IN_CH 64
#define HID 128

// ---------------- degree count (float, exact up to 2^24) ----------------
__global__ __launch_bounds__(256) void degree_kernel(const int* __restrict__ dst,
                                                     float* __restrict__ cnt, int E) {
    int i = blockIdx.x * blockDim.x + threadIdx.x;
    if (i < E) atomicAdd(&cnt[dst[i]], 1.0f);
}

// ------------- scatter-add of features along edges (atomics) -------------
// one thread per (edge, channel); C = 1<<LOGC channels
template <int LOGC>
__global__ __launch_bounds__(256) void scatter_kernel(const float* __restrict__ feat,
                                                      const int* __restrict__ src,
                                                      const int* __restrict__ dst,
                                                      float* __restrict__ agg, int total) {
    int idx = blockIdx.x * blockDim.x + threadIdx.x;
    if (idx >= total) return;
    int e = idx >> LOGC;
    int c = idx & ((1 << LOGC) - 1);
    int s = src[e];
    int d = dst[e];
    atomicAdd(&agg[((size_t)d << LOGC) + c], feat[((size_t)s << LOGC) + c]);
}

// ------------- fused SAGE layer: relu(mean@Wn + h@Ws + b) -------------
// A matrices are [N,K]; weights [K,128]; out [N,128].
// 32 rows/block, 256 threads, each thread 4 rows x 4 cols.
template <int K, bool RELU>
__global__ __launch_bounds__(256) void sage_gemm(const float* __restrict__ agg,
                                                 const float* __restrict__ cnt,
                                                 const float* __restrict__ h,
                                                 const float* __restrict__ Wn,
                                                 const float* __restrict__ Ws,
                                                 const float* __restrict__ bias,
                                                 float* __restrict__ out) {
    __shared__ float Am[32][K + 1];  // +1 pad: LDS bank-conflict break
    __shared__ float Ah[32][K + 1];
    const int t = threadIdx.x;
    const int row0 = blockIdx.x * 32;  // N % 32 == 0 (100000 = 32*3125)

    constexpr int K4 = K / 4;
    for (int i = t; i < 32 * K4; i += 256) {
        int r = i / K4;
        int c4 = i % K4;
        float inv = 1.0f / fmaxf(cnt[row0 + r], 1.0f);
        float4 a = ((const float4*)(agg + (size_t)(row0 + r) * K))[c4];
        Am[r][c4 * 4 + 0] = a.x * inv;
        Am[r][c4 * 4 + 1] = a.y * inv;
        Am[r][c4 * 4 + 2] = a.z * inv;
        Am[r][c4 * 4 + 3] = a.w * inv;
        float4 b = ((const float4*)(h + (size_t)(row0 + r) * K))[c4];
        Ah[r][c4 * 4 + 0] = b.x;
        Ah[r][c4 * 4 + 1] = b.y;
        Ah[r][c4 * 4 + 2] = b.z;
        Ah[r][c4 * 4 + 3] = b.w;
    }
    __syncthreads();

    const int rg = t >> 5;        // 0..7
    const int cg = t & 31;        // 0..31
    const int r0 = rg * 4;
    const int c0 = cg * 4;

    float acc[4][4] = {};
    for (int k = 0; k < K; ++k) {
        float4 wn = *(const float4*)(Wn + (size_t)k * HID + c0);
        float4 ws = *(const float4*)(Ws + (size_t)k * HID + c0);
#pragma unroll
        for (int r = 0; r < 4; ++r) {
            float am = Am[r0 + r][k];
            float ah = Ah[r0 + r][k];
            acc[r][0] += am * wn.x;
            acc[r][1] += am * wn.y;
            acc[r][2] += am * wn.z;
            acc[r][3] += am * wn.w;
            acc[r][0] += ah * ws.x;
            acc[r][1] += ah * ws.y;
            acc[r][2] += ah * ws.z;
            acc[r][3] += ah * ws.w;
        }
    }

    float4 bv = *(const float4*)(bias + c0);
#pragma unroll
    for (int r = 0; r < 4; ++r) {
        float4 o;
        o.x = acc[r][0] + bv.x;
        o.y = acc[r][1] + bv.y;
        o.z = acc[r][2] + bv.z;
        o.w = acc[r][3] + bv.w;
        if (RELU) {
            o.x = fmaxf(o.x, 0.0f);
            o.y = fmaxf(o.y, 0.0f);
            o.z = fmaxf(o.z, 0.0f);
            o.w = fmaxf(o.w, 0.0f);
        }
        *(float4*)(out + (size_t)(row0 + r0 + r) * HID + c0) = o;
    }
}

// ---------------- final fc: [N,128] @ [128,2] + b ----------------
__global__ __launch_bounds__(256) void fc_kernel(const float* __restrict__ h,
                                                 const float* __restrict__ W,
                                                 const float* __restrict__ b,
                                                 float* __restrict__ out, int N) {
    __shared__ float Wl[256];
    Wl[threadIdx.x] = W[threadIdx.x];
    __syncthreads();
    int i = blockIdx.x * blockDim.x + threadIdx.x;
    if (i >= N) return;
    const float4* hp = (const float4*)(h + (size_t)i * HID);
    float a0 = 0.0f, a1 = 0.0f;
#pragma unroll
    for (int k4 = 0; k4 < HID / 4; ++k4) {
        float4 v = hp[k4];
        a0 += v.x * Wl[(k4 * 4 + 0) * 2 + 0];
        a1 += v.x * Wl[(k4 * 4 + 0) * 2 + 1];
        a0 += v.y * Wl[(k4 * 4 + 1) * 2 + 0];
        a1 += v.y * Wl[(k4 * 4 + 1) * 2 + 1];
        a0 += v.z * Wl[(k4 * 4 + 2) * 2 + 0];
        a1 += v.z * Wl[(k4 * 4 + 2) * 2 + 1];
        a0 += v.w * Wl[(k4 * 4 + 3) * 2 + 0];
        a1 += v.w * Wl[(k4 * 4 + 3) * 2 + 1];
    }
    out[(size_t)i * 2 + 0] = a0 + b[0];
    out[(size_t)i * 2 + 1] = a1 + b[1];
}

extern "C" void kernel_launch(void* const* d_in, const int* in_sizes, int n_in,
                              void* d_out, int out_size, void* d_ws, size_t ws_size,
                              hipStream_t stream) {
    const float* x   = (const float*)d_in[0];
    const int*   ei  = (const int*)d_in[1];
    const float* Wn0 = (const float*)d_in[2];
    const float* Ws0 = (const float*)d_in[3];
    const float* b0  = (const float*)d_in[4];
    const float* Wn1 = (const float*)d_in[5];
    const float* Ws1 = (const float*)d_in[6];
    const float* b1  = (const float*)d_in[7];
    const float* fcw = (const float*)d_in[8];
    const float* fcb = (const float*)d_in[9];
    float* out = (float*)d_out;

    const int E = in_sizes[1] / 2;
    const int* src = ei;
    const int* dst = ei + E;
    const int N = N_NODES;

    // workspace layout
    char* ws = (char*)d_ws;
    float* cnt = (float*)ws;                                   // 400 KB (padded to 512K)
    float* agg = (float*)(ws + (1 << 19));                     // 51.2 MB (layer0 uses 25.6)
    float* h1  = (float*)(ws + (1 << 19) + 51200000);          // 51.2 MB
    float* h2  = (float*)(ws + (1 << 19) + 102400000);         // 51.2 MB

    hipMemsetAsync(cnt, 0, (size_t)N * sizeof(float), stream);
    hipMemsetAsync(agg, 0, (size_t)N * IN_CH * sizeof(float), stream);

    degree_kernel<<<(E + 255) / 256, 256, 0, stream>>>(dst, cnt, E);

    // layer 0 aggregation: x[src] -> agg[dst], C=64
    {
        int total = E * IN_CH;  // 102.4M
        scatter_kernel<6><<<(total + 255) / 256, 256, 0, stream>>>(x, src, dst, agg, total);
    }
    sage_gemm<IN_CH, true><<<N / 32, 256, 0, stream>>>(agg, cnt, x, Wn0, Ws0, b0, h1);

    // layer 1 aggregation: h1[src] -> agg[dst], C=128
    hipMemsetAsync(agg, 0, (size_t)N * HID * sizeof(float), stream);
    {
        int total = E * HID;  // 204.8M
        scatter_kernel<7><<<(total + 255) / 256, 256, 0, stream>>>(h1, src, dst, agg, total);
    }
    sage_gemm<HID, true><<<N / 32, 256, 0, stream>>>(agg, cnt, h1, Wn1, Ws1, b1, h2);

    fc_kernel<<<(N + 255) / 256, 256, 0, stream>>>(h2, fcw, fcb, out, N);
}

// Round 2
// 666.973 us; speedup vs baseline: 2.1028x; 2.1028x over previous
//
#include <hip/hip_runtime.h>

#define N_NODES 100000
#define IN_CH 64
#define HID 128
#define SCAN_BLK 256

// ================= CSR build =================

__global__ __launch_bounds__(256) void degree_kernel(const int* __restrict__ dst,
                                                     int* __restrict__ deg, int E) {
    int i = blockIdx.x * blockDim.x + threadIdx.x;
    if (i < E) atomicAdd(&deg[dst[i]], 1);
}

// phase 1: per-block inclusive scan of deg -> inc, block sums -> bsum
__global__ __launch_bounds__(SCAN_BLK) void scan1_kernel(const int* __restrict__ deg,
                                                         int* __restrict__ inc,
                                                         int* __restrict__ bsum, int N) {
    __shared__ int s[SCAN_BLK];
    int i = blockIdx.x * SCAN_BLK + threadIdx.x;
    int v = (i < N) ? deg[i] : 0;
    s[threadIdx.x] = v;
    __syncthreads();
#pragma unroll
    for (int off = 1; off < SCAN_BLK; off <<= 1) {
        int t = (threadIdx.x >= off) ? s[threadIdx.x - off] : 0;
        __syncthreads();
        s[threadIdx.x] += t;
        __syncthreads();
    }
    if (i < N) inc[i] = s[threadIdx.x];
    if (threadIdx.x == SCAN_BLK - 1) bsum[blockIdx.x] = s[SCAN_BLK - 1];
}

// phase 2: single block, exclusive scan of NB block sums (NB <= 512)
__global__ __launch_bounds__(512) void scan2_kernel(const int* __restrict__ bsum,
                                                    int* __restrict__ bexcl, int NB) {
    __shared__ int s[512];
    int t = threadIdx.x;
    int orig = (t < NB) ? bsum[t] : 0;
    s[t] = orig;
    __syncthreads();
#pragma unroll
    for (int off = 1; off < 512; off <<= 1) {
        int v = (t >= off) ? s[t - off] : 0;
        __syncthreads();
        s[t] += v;
        __syncthreads();
    }
    if (t < NB) bexcl[t] = s[t] - orig;
}

// phase 3: ptr (exclusive, N+1) and cursor init
__global__ __launch_bounds__(256) void scan3_kernel(const int* __restrict__ deg,
                                                    const int* __restrict__ inc,
                                                    const int* __restrict__ bexcl,
                                                    int* __restrict__ ptr,
                                                    int* __restrict__ cursor, int N) {
    int i = blockIdx.x * blockDim.x + threadIdx.x;
    if (i >= N) return;
    int ginc = bexcl[i >> 8] + inc[i];
    ptr[i + 1] = ginc;
    cursor[i] = ginc - deg[i];
    if (i == 0) ptr[0] = 0;
}

__global__ __launch_bounds__(256) void bucket_kernel(const int* __restrict__ src,
                                                     const int* __restrict__ dst,
                                                     int* __restrict__ cursor,
                                                     int* __restrict__ sorted_src, int E) {
    int e = blockIdx.x * blockDim.x + threadIdx.x;
    if (e >= E) return;
    int pos = atomicAdd(&cursor[dst[e]], 1);
    sorted_src[pos] = src[e];
}

// ================= gather + mean =================
// one wave per node; C channels, V=C/64 floats per lane
template <int C>
__global__ __launch_bounds__(256) void gather_mean(const int* __restrict__ ptr,
                                                   const int* __restrict__ srcs,
                                                   const float* __restrict__ feat,
                                                   float* __restrict__ mean, int N) {
    int w = (blockIdx.x * blockDim.x + threadIdx.x) >> 6;
    if (w >= N) return;
    int lane = threadIdx.x & 63;
    int s0 = ptr[w], s1 = ptr[w + 1];
    constexpr int V = C / 64;
    float acc0[V] = {}, acc1[V] = {};
    int j = s0;
    for (; j + 2 <= s1; j += 2) {
        int sA = srcs[j];
        int sB = srcs[j + 1];
        const float* rA = feat + (size_t)sA * C;
        const float* rB = feat + (size_t)sB * C;
#pragma unroll
        for (int v = 0; v < V; ++v) {
            acc0[v] += rA[lane + v * 64];
            acc1[v] += rB[lane + v * 64];
        }
    }
    if (j < s1) {
        const float* rA = feat + (size_t)srcs[j] * C;
#pragma unroll
        for (int v = 0; v < V; ++v) acc0[v] += rA[lane + v * 64];
    }
    float inv = (s1 > s0) ? 1.0f / (float)(s1 - s0) : 0.0f;
    float* o = mean + (size_t)w * C;
#pragma unroll
    for (int v = 0; v < V; ++v) o[lane + v * 64] = (acc0[v] + acc1[v]) * inv;
}

// ================= fused SAGE layer: relu(mean@Wn + h@Ws + b) =================
// 32 rows/block, 256 threads, each thread 4 rows x 4 cols. Optional fused FC.
template <int K, bool FUSE_FC>
__global__ __launch_bounds__(256) void sage_gemm(const float* __restrict__ mean,
                                                 const float* __restrict__ h,
                                                 const float* __restrict__ Wn,
                                                 const float* __restrict__ Ws,
                                                 const float* __restrict__ bias,
                                                 const float* __restrict__ fcw,
                                                 const float* __restrict__ fcb,
                                                 float* __restrict__ out) {
    __shared__ float Am[32][K + 1];
    __shared__ float Ah[32][K + 1];
    const int t = threadIdx.x;
    const int row0 = blockIdx.x * 32;  // 100000 % 32 == 0

    constexpr int K4 = K / 4;
    for (int i = t; i < 32 * K4; i += 256) {
        int r = i / K4;
        int c4 = i % K4;
        float4 a = ((const float4*)(mean + (size_t)(row0 + r) * K))[c4];
        Am[r][c4 * 4 + 0] = a.x;
        Am[r][c4 * 4 + 1] = a.y;
        Am[r][c4 * 4 + 2] = a.z;
        Am[r][c4 * 4 + 3] = a.w;
        float4 b = ((const float4*)(h + (size_t)(row0 + r) * K))[c4];
        Ah[r][c4 * 4 + 0] = b.x;
        Ah[r][c4 * 4 + 1] = b.y;
        Ah[r][c4 * 4 + 2] = b.z;
        Ah[r][c4 * 4 + 3] = b.w;
    }
    __syncthreads();

    const int rg = t >> 5;   // 0..7 row group
    const int cg = t & 31;   // 0..31 col group
    const int r0 = rg * 4;
    const int c0 = cg * 4;

    float acc[4][4] = {};
    for (int k = 0; k < K; ++k) {
        float4 wn = *(const float4*)(Wn + (size_t)k * HID + c0);
        float4 ws = *(const float4*)(Ws + (size_t)k * HID + c0);
#pragma unroll
        for (int r = 0; r < 4; ++r) {
            float am = Am[r0 + r][k];
            float ah = Ah[r0 + r][k];
            acc[r][0] += am * wn.x;
            acc[r][1] += am * wn.y;
            acc[r][2] += am * wn.z;
            acc[r][3] += am * wn.w;
            acc[r][0] += ah * ws.x;
            acc[r][1] += ah * ws.y;
            acc[r][2] += ah * ws.z;
            acc[r][3] += ah * ws.w;
        }
    }

    float4 bv = *(const float4*)(bias + c0);
#pragma unroll
    for (int r = 0; r < 4; ++r) {
        acc[r][0] = fmaxf(acc[r][0] + bv.x, 0.0f);
        acc[r][1] = fmaxf(acc[r][1] + bv.y, 0.0f);
        acc[r][2] = fmaxf(acc[r][2] + bv.z, 0.0f);
        acc[r][3] = fmaxf(acc[r][3] + bv.w, 0.0f);
    }

    if (!FUSE_FC) {
#pragma unroll
        for (int r = 0; r < 4; ++r) {
            float4 o;
            o.x = acc[r][0];
            o.y = acc[r][1];
            o.z = acc[r][2];
            o.w = acc[r][3];
            *(float4*)(out + (size_t)(row0 + r0 + r) * HID + c0) = o;
        }
    } else {
        // out[row,k] = fcb[k] + sum_c h2[row,c]*fcw[c*2+k]; reduce over the 32
        // cg-threads (contiguous half-wave) via shfl_xor width 32.
        float w0[4], w1[4];
#pragma unroll
        for (int jj = 0; jj < 4; ++jj) {
            w0[jj] = fcw[(c0 + jj) * 2 + 0];
            w1[jj] = fcw[(c0 + jj) * 2 + 1];
        }
#pragma unroll
        for (int r = 0; r < 4; ++r) {
            float o0 = acc[r][0] * w0[0] + acc[r][1] * w0[1] + acc[r][2] * w0[2] + acc[r][3] * w0[3];
            float o1 = acc[r][0] * w1[0] + acc[r][1] * w1[1] + acc[r][2] * w1[2] + acc[r][3] * w1[3];
#pragma unroll
            for (int m = 16; m >= 1; m >>= 1) {
                o0 += __shfl_xor(o0, m, 32);
                o1 += __shfl_xor(o1, m, 32);
            }
            if (cg == 0) {
                out[(size_t)(row0 + r0 + r) * 2 + 0] = o0 + fcb[0];
                out[(size_t)(row0 + r0 + r) * 2 + 1] = o1 + fcb[1];
            }
        }
    }
}

extern "C" void kernel_launch(void* const* d_in, const int* in_sizes, int n_in,
                              void* d_out, int out_size, void* d_ws, size_t ws_size,
                              hipStream_t stream) {
    const float* x   = (const float*)d_in[0];
    const int*   ei  = (const int*)d_in[1];
    const float* Wn0 = (const float*)d_in[2];
    const float* Ws0 = (const float*)d_in[3];
    const float* b0  = (const float*)d_in[4];
    const float* Wn1 = (const float*)d_in[5];
    const float* Ws1 = (const float*)d_in[6];
    const float* b1  = (const float*)d_in[7];
    const float* fcw = (const float*)d_in[8];
    const float* fcb = (const float*)d_in[9];
    float* out = (float*)d_out;

    const int E = in_sizes[1] / 2;
    const int* src = ei;
    const int* dst = ei + E;
    const int N = N_NODES;
    const int NB = (N + SCAN_BLK - 1) / SCAN_BLK;  // 391

    // workspace layout
    char* ws = (char*)d_ws;
    size_t off = 0;
    int* deg    = (int*)(ws + off); off += (size_t)N * 4;          // 400000
    int* inc    = (int*)(ws + off); off += (size_t)N * 4;
    int* bsum   = (int*)(ws + off); off += 4096;
    int* bexcl  = (int*)(ws + off); off += 4096;
    int* ptr    = (int*)(ws + off); off += (size_t)(N + 1) * 4 + 60; off &= ~(size_t)63;
    int* cursor = (int*)(ws + off); off += (size_t)N * 4;
    int* sorted = (int*)(ws + off); off += (size_t)E * 4;          // 6.4 MB
    off = (off + 255) & ~(size_t)255;
    float* agg = (float*)(ws + off); off += (size_t)N * HID * 4;   // 51.2 MB
    float* h1  = (float*)(ws + off); off += (size_t)N * HID * 4;   // 51.2 MB

    // ---- CSR build ----
    hipMemsetAsync(deg, 0, (size_t)N * 4, stream);
    degree_kernel<<<(E + 255) / 256, 256, 0, stream>>>(dst, deg, E);
    scan1_kernel<<<NB, SCAN_BLK, 0, stream>>>(deg, inc, bsum, N);
    scan2_kernel<<<1, 512, 0, stream>>>(bsum, bexcl, NB);
    scan3_kernel<<<NB, 256, 0, stream>>>(deg, inc, bexcl, ptr, cursor, N);
    bucket_kernel<<<(E + 255) / 256, 256, 0, stream>>>(src, dst, cursor, sorted, E);

    // ---- layer 0 ----
    gather_mean<IN_CH><<<(N + 3) / 4, 256, 0, stream>>>(ptr, sorted, x, agg, N);
    sage_gemm<IN_CH, false><<<N / 32, 256, 0, stream>>>(agg, x, Wn0, Ws0, b0, nullptr, nullptr, h1);

    // ---- layer 1 + fused fc ----
    gather_mean<HID><<<(N + 3) / 4, 256, 0, stream>>>(ptr, sorted, h1, agg, N);
    sage_gemm<HID, true><<<N / 32, 256, 0, stream>>>(agg, h1, Wn1, Ws1, b1, fcw, fcb, out);
}

// Round 3
// 507.588 us; speedup vs baseline: 2.7631x; 1.3140x over previous
//
#include <hip/hip_runtime.h>

#define N_NODES 100000
#define IN_CH 64
#define HID 128
#define SCAN_BLK 256

typedef short short8 __attribute__((ext_vector_type(8)));
typedef float floatx4 __attribute__((ext_vector_type(4)));

__device__ __forceinline__ unsigned short f2bf(float f) {
    unsigned u = __builtin_bit_cast(unsigned, f);
    u += 0x7fffu + ((u >> 16) & 1u);  // RNE
    return (unsigned short)(u >> 16);
}
__device__ __forceinline__ float bf2f(unsigned short h) {
    unsigned u = ((unsigned)h) << 16;
    return __builtin_bit_cast(float, u);
}

// ================= CSR build =================

__global__ __launch_bounds__(256) void degree_kernel(const int* __restrict__ dst,
                                                     int* __restrict__ deg, int E) {
    int i = blockIdx.x * blockDim.x + threadIdx.x;
    if (i < E) atomicAdd(&deg[dst[i]], 1);
}

__global__ __launch_bounds__(SCAN_BLK) void scan1_kernel(const int* __restrict__ deg,
                                                         int* __restrict__ inc,
                                                         int* __restrict__ bsum, int N) {
    __shared__ int s[SCAN_BLK];
    int i = blockIdx.x * SCAN_BLK + threadIdx.x;
    int v = (i < N) ? deg[i] : 0;
    s[threadIdx.x] = v;
    __syncthreads();
#pragma unroll
    for (int off = 1; off < SCAN_BLK; off <<= 1) {
        int t = (threadIdx.x >= off) ? s[threadIdx.x - off] : 0;
        __syncthreads();
        s[threadIdx.x] += t;
        __syncthreads();
    }
    if (i < N) inc[i] = s[threadIdx.x];
    if (threadIdx.x == SCAN_BLK - 1) bsum[blockIdx.x] = s[SCAN_BLK - 1];
}

__global__ __launch_bounds__(512) void scan2_kernel(const int* __restrict__ bsum,
                                                    int* __restrict__ bexcl, int NB) {
    __shared__ int s[512];
    int t = threadIdx.x;
    int orig = (t < NB) ? bsum[t] : 0;
    s[t] = orig;
    __syncthreads();
#pragma unroll
    for (int off = 1; off < 512; off <<= 1) {
        int v = (t >= off) ? s[t - off] : 0;
        __syncthreads();
        s[t] += v;
        __syncthreads();
    }
    if (t < NB) bexcl[t] = s[t] - orig;
}

__global__ __launch_bounds__(256) void scan3_kernel(const int* __restrict__ deg,
                                                    const int* __restrict__ inc,
                                                    const int* __restrict__ bexcl,
                                                    int* __restrict__ ptr,
                                                    int* __restrict__ cursor, int N) {
    int i = blockIdx.x * blockDim.x + threadIdx.x;
    if (i >= N) return;
    int ginc = bexcl[i >> 8] + inc[i];
    ptr[i + 1] = ginc;
    cursor[i] = ginc - deg[i];
    if (i == 0) ptr[0] = 0;
}

__global__ __launch_bounds__(256) void bucket_kernel(const int* __restrict__ src,
                                                     const int* __restrict__ dst,
                                                     int* __restrict__ cursor,
                                                     int* __restrict__ sorted_src, int E) {
    int e = blockIdx.x * blockDim.x + threadIdx.x;
    if (e >= E) return;
    int pos = atomicAdd(&cursor[dst[e]], 1);
    sorted_src[pos] = src[e];
}

// ================= fp32 -> bf16 convert =================
__global__ __launch_bounds__(256) void convert_bf_kernel(const float* __restrict__ in,
                                                         unsigned short* __restrict__ out,
                                                         int n4) {
    int i = blockIdx.x * blockDim.x + threadIdx.x;
    if (i >= n4) return;
    float4 v = ((const float4*)in)[i];
    ushort4 o;
    o.x = f2bf(v.x); o.y = f2bf(v.y); o.z = f2bf(v.z); o.w = f2bf(v.w);
    ((ushort4*)out)[i] = o;
}

// ================= weight pack into MFMA B-fragment order =================
// Bpack chunk index ((s*8 + t)*64 + lane), 8 bf16 each:
//   b_frag[j] = Wcat[k = s*32 + (lane>>4)*8 + j][n = t*16 + (lane&15)]
// Wcat = [Wn ; Ws] along k (KT = 2K rows).
template <int K>
__global__ __launch_bounds__(256) void pack_w_kernel(const float* __restrict__ Wn,
                                                     const float* __restrict__ Ws,
                                                     unsigned short* __restrict__ Bpack) {
    constexpr int KT = 2 * K;
    constexpr int TOT = (KT / 32) * 8 * 64;
    int idx = blockIdx.x * blockDim.x + threadIdx.x;
    if (idx >= TOT) return;
    int s = idx >> 9;
    int rem = idx & 511;
    int t = rem >> 6;
    int lane = rem & 63;
    int quad = lane >> 4;
    int n = t * 16 + (lane & 15);
    unsigned short v[8];
#pragma unroll
    for (int j = 0; j < 8; ++j) {
        int k = s * 32 + quad * 8 + j;
        float w = (k < K) ? Wn[(size_t)k * HID + n] : Ws[(size_t)(k - K) * HID + n];
        v[j] = f2bf(w);
    }
    *(short8*)(Bpack + (size_t)idx * 8) = *(short8*)v;
}

// ================= gather + mean (bf16 in/out, fp32 accum) =================
// one wave per node; V = C/64 bf16 per lane
template <int C>
__global__ __launch_bounds__(256) void gather_mean(const int* __restrict__ ptr,
                                                   const int* __restrict__ srcs,
                                                   const unsigned short* __restrict__ feat,
                                                   unsigned short* __restrict__ mean, int N) {
    int w = (blockIdx.x * blockDim.x + threadIdx.x) >> 6;
    if (w >= N) return;
    int lane = threadIdx.x & 63;
    int s0 = ptr[w], s1 = ptr[w + 1];
    constexpr int V = C / 64;
    float acc0[V] = {}, acc1[V] = {};
    int j = s0;
    for (; j + 2 <= s1; j += 2) {
        const unsigned short* rA = feat + (size_t)srcs[j] * C;
        const unsigned short* rB = feat + (size_t)srcs[j + 1] * C;
        if (V == 1) {
            unsigned short a = rA[lane];
            unsigned short b = rB[lane];
            acc0[0] += bf2f(a);
            acc1[0] += bf2f(b);
        } else {
            uint a = *(const uint*)(rA + lane * 2);
            uint b = *(const uint*)(rB + lane * 2);
            acc0[0] += bf2f((unsigned short)(a & 0xffff));
            acc0[1] += bf2f((unsigned short)(a >> 16));
            acc1[0] += bf2f((unsigned short)(b & 0xffff));
            acc1[1] += bf2f((unsigned short)(b >> 16));
        }
    }
    if (j < s1) {
        const unsigned short* rA = feat + (size_t)srcs[j] * C;
        if (V == 1) {
            acc0[0] += bf2f(rA[lane]);
        } else {
            uint a = *(const uint*)(rA + lane * 2);
            acc0[0] += bf2f((unsigned short)(a & 0xffff));
            acc0[1] += bf2f((unsigned short)(a >> 16));
        }
    }
    float inv = (s1 > s0) ? 1.0f / (float)(s1 - s0) : 0.0f;
    if (V == 1) {
        mean[(size_t)w * C + lane] = f2bf((acc0[0] + acc1[0]) * inv);
    } else {
        unsigned short lo16 = f2bf((acc0[0] + acc1[0]) * inv);
        unsigned short hi16 = f2bf((acc0[1] + acc1[1]) * inv);
        *(uint*)(mean + (size_t)w * C + lane * 2) = (uint)lo16 | ((uint)hi16 << 16);
    }
}

// ================= MFMA SAGE GEMM: relu([mean|h] @ [Wn;Ws] + b) =================
// block = 256 thr = 4 waves; tile = 64 rows x 128 cols; wave w -> rows w*16..w*16+15.
// A staged in LDS (pad 8 ushorts -> 2-way banking, free). B from Bpack (L2-hot).
template <int KT, bool FUSE_FC>
__global__ __launch_bounds__(256) void sage_gemm_mfma(const unsigned short* __restrict__ meanb,
                                                      const unsigned short* __restrict__ hb,
                                                      const unsigned short* __restrict__ Bpack,
                                                      const float* __restrict__ bias,
                                                      const float* __restrict__ fcw,
                                                      const float* __restrict__ fcb,
                                                      unsigned short* __restrict__ outb,
                                                      float* __restrict__ outf, int N) {
    constexpr int KH = KT / 2;
    constexpr int LDA = KT + 8;  // ushorts; +8 keeps 16B alignment, breaks bank stride
    __shared__ unsigned short As[64 * LDA];
    const int t = threadIdx.x;
    const int row0 = blockIdx.x * 64;

    constexpr int SEGS = KT / 8;  // 16B segments per row
    for (int c = t; c < 64 * SEGS; c += 256) {
        int r = c / SEGS, seg = c % SEGS;
        int rsrc = row0 + r;
        if (rsrc >= N) rsrc = N - 1;
        const unsigned short* srcp = (seg < SEGS / 2)
                                         ? meanb + (size_t)rsrc * KH + seg * 8
                                         : hb + (size_t)rsrc * KH + (seg - SEGS / 2) * 8;
        *(uint4*)&As[r * LDA + seg * 8] = *(const uint4*)srcp;
    }
    __syncthreads();

    const int lane = t & 63;
    const int wave = t >> 6;
    const int quad = lane >> 4;
    const int lo = lane & 15;

    floatx4 acc[8];
#pragma unroll
    for (int i = 0; i < 8; ++i)
#pragma unroll
        for (int r = 0; r < 4; ++r) acc[i][r] = 0.0f;

    const unsigned short* abase = &As[(wave * 16 + lo) * LDA + quad * 8];
#pragma unroll
    for (int s = 0; s < KT / 32; ++s) {
        short8 a = *(const short8*)(abase + s * 32);
        const short8* bp = (const short8*)Bpack + (size_t)(s * 8) * 64 + lane;
#pragma unroll
        for (int tt = 0; tt < 8; ++tt) {
            short8 b = bp[tt * 64];
            acc[tt] = __builtin_amdgcn_mfma_f32_16x16x32_bf16(a, b, acc[tt], 0, 0, 0);
        }
    }

    // C/D: col = lane&15 (+16*tt), row = quad*4 + reg (+16*wave)
    if (!FUSE_FC) {
#pragma unroll
        for (int tt = 0; tt < 8; ++tt) {
            int col = tt * 16 + lo;
            float bv = bias[col];
#pragma unroll
            for (int r = 0; r < 4; ++r) {
                int row = row0 + wave * 16 + quad * 4 + r;
                if (row < N) {
                    float v = fmaxf(acc[tt][r] + bv, 0.0f);
                    outb[(size_t)row * HID + col] = f2bf(v);
                }
            }
        }
    } else {
        float o0[4] = {}, o1[4] = {};
#pragma unroll
        for (int tt = 0; tt < 8; ++tt) {
            int col = tt * 16 + lo;
            float bv = bias[col];
            float w0 = fcw[col * 2 + 0];
            float w1 = fcw[col * 2 + 1];
#pragma unroll
            for (int r = 0; r < 4; ++r) {
                float v = fmaxf(acc[tt][r] + bv, 0.0f);
                o0[r] += v * w0;
                o1[r] += v * w1;
            }
        }
#pragma unroll
        for (int r = 0; r < 4; ++r) {
#pragma unroll
            for (int m = 8; m >= 1; m >>= 1) {
                o0[r] += __shfl_xor(o0[r], m, 16);
                o1[r] += __shfl_xor(o1[r], m, 16);
            }
        }
        if (lo == 0) {
#pragma unroll
            for (int r = 0; r < 4; ++r) {
                int row = row0 + wave * 16 + quad * 4 + r;
                if (row < N) {
                    outf[(size_t)row * 2 + 0] = o0[r] + fcb[0];
                    outf[(size_t)row * 2 + 1] = o1[r] + fcb[1];
                }
            }
        }
    }
}

extern "C" void kernel_launch(void* const* d_in, const int* in_sizes, int n_in,
                              void* d_out, int out_size, void* d_ws, size_t ws_size,
                              hipStream_t stream) {
    const float* x   = (const float*)d_in[0];
    const int*   ei  = (const int*)d_in[1];
    const float* Wn0 = (const float*)d_in[2];
    const float* Ws0 = (const float*)d_in[3];
    const float* b0  = (const float*)d_in[4];
    const float* Wn1 = (const float*)d_in[5];
    const float* Ws1 = (const float*)d_in[6];
    const float* b1  = (const float*)d_in[7];
    const float* fcw = (const float*)d_in[8];
    const float* fcb = (const float*)d_in[9];
    float* out = (float*)d_out;

    const int E = in_sizes[1] / 2;
    const int* src = ei;
    const int* dst = ei + E;
    const int N = N_NODES;
    const int NB = (N + SCAN_BLK - 1) / SCAN_BLK;  // 391

    // workspace layout
    char* ws = (char*)d_ws;
    size_t off = 0;
    int* deg    = (int*)(ws + off); off += (size_t)N * 4;
    int* inc    = (int*)(ws + off); off += (size_t)N * 4;
    int* bsum   = (int*)(ws + off); off += 4096;
    int* bexcl  = (int*)(ws + off); off += 4096;
    int* ptr    = (int*)(ws + off); off += (size_t)(N + 1) * 4 + 60; off &= ~(size_t)63;
    int* cursor = (int*)(ws + off); off += (size_t)N * 4;
    int* sorted = (int*)(ws + off); off += (size_t)E * 4;
    off = (off + 255) & ~(size_t)255;
    unsigned short* x_bf   = (unsigned short*)(ws + off); off += (size_t)N * IN_CH * 2;
    unsigned short* mean0  = (unsigned short*)(ws + off); off += (size_t)N * IN_CH * 2;
    unsigned short* h1_bf  = (unsigned short*)(ws + off); off += (size_t)N * HID * 2;
    unsigned short* mean1  = (unsigned short*)(ws + off); off += (size_t)N * HID * 2;
    unsigned short* Bpack0 = (unsigned short*)(ws + off); off += (size_t)(2 * IN_CH / 32) * 8 * 64 * 8 * 2;
    unsigned short* Bpack1 = (unsigned short*)(ws + off); off += (size_t)(2 * HID / 32) * 8 * 64 * 8 * 2;

    // ---- CSR build ----
    hipMemsetAsync(deg, 0, (size_t)N * 4, stream);
    degree_kernel<<<(E + 255) / 256, 256, 0, stream>>>(dst, deg, E);
    scan1_kernel<<<NB, SCAN_BLK, 0, stream>>>(deg, inc, bsum, N);
    scan2_kernel<<<1, 512, 0, stream>>>(bsum, bexcl, NB);
    scan3_kernel<<<NB, 256, 0, stream>>>(deg, inc, bexcl, ptr, cursor, N);
    bucket_kernel<<<(E + 255) / 256, 256, 0, stream>>>(src, dst, cursor, sorted, E);

    // ---- conversions / weight packing ----
    {
        int n4 = N * IN_CH / 4;
        convert_bf_kernel<<<(n4 + 255) / 256, 256, 0, stream>>>(x, x_bf, n4);
    }
    pack_w_kernel<IN_CH><<<((2 * IN_CH / 32) * 8 * 64 + 255) / 256, 256, 0, stream>>>(Wn0, Ws0, Bpack0);
    pack_w_kernel<HID><<<((2 * HID / 32) * 8 * 64 + 255) / 256, 256, 0, stream>>>(Wn1, Ws1, Bpack1);

    // ---- layer 0 ----
    gather_mean<IN_CH><<<(N * 64 + 255) / 256, 256, 0, stream>>>(ptr, sorted, x_bf, mean0, N);
    sage_gemm_mfma<2 * IN_CH, false><<<(N + 63) / 64, 256, 0, stream>>>(
        mean0, x_bf, Bpack0, b0, nullptr, nullptr, h1_bf, nullptr, N);

    // ---- layer 1 + fused fc ----
    gather_mean<HID><<<(N * 64 + 255) / 256, 256, 0, stream>>>(ptr, sorted, h1_bf, mean1, N);
    sage_gemm_mfma<2 * HID, true><<<(N + 63) / 64, 256, 0, stream>>>(
        mean1, h1_bf, Bpack1, b1, fcw, fcb, nullptr, out, N);
}

// Round 4
// 366.928 us; speedup vs baseline: 3.8223x; 1.3833x over previous
//
#include <hip/hip_runtime.h>

#define N_NODES 100000
#define IN_CH 64
#define HID 128
#define NBUCK ((N_NODES + 511) >> 9)   // 196 coarse buckets of 512 nodes
#define NCB 256                        // edge-chunk blocks for hist/bin

typedef short short8 __attribute__((ext_vector_type(8)));
typedef float floatx4 __attribute__((ext_vector_type(4)));

__device__ __forceinline__ unsigned short f2bf(float f) {
    unsigned u = __builtin_bit_cast(unsigned, f);
    u += 0x7fffu + ((u >> 16) & 1u);  // RNE
    return (unsigned short)(u >> 16);
}
__device__ __forceinline__ float bf2f(unsigned short h) {
    unsigned u = ((unsigned)h) << 16;
    return __builtin_bit_cast(float, u);
}

// ================= binned counting-sort CSR build (no global atomics) =================

// phase A: per-(bucket, block) histogram of dst>>9
__global__ __launch_bounds__(256) void hist_kernel(const int* __restrict__ dst,
                                                   int* __restrict__ table, int E, int chunk) {
    __shared__ int h[NBUCK];
    for (int i = threadIdx.x; i < NBUCK; i += 256) h[i] = 0;
    __syncthreads();
    int e0 = blockIdx.x * chunk;
    int e1 = min(E, e0 + chunk);
    for (int e = e0 + threadIdx.x; e < e1; e += 256) atomicAdd(&h[dst[e] >> 9], 1);
    __syncthreads();
    for (int i = threadIdx.x; i < NBUCK; i += 256) table[i * NCB + blockIdx.x] = h[i];
}

// phase B1: per-bucket exclusive scan over the NCB block counts; bucket totals out
__global__ __launch_bounds__(256) void scanb1_kernel(int* __restrict__ table,
                                                     int* __restrict__ tot) {
    __shared__ int s[NCB];
    int b = blockIdx.x, t = threadIdx.x;
    int c = table[b * NCB + t];
    s[t] = c;
    __syncthreads();
#pragma unroll
    for (int off = 1; off < NCB; off <<= 1) {
        int v = (t >= off) ? s[t - off] : 0;
        __syncthreads();
        s[t] += v;
        __syncthreads();
    }
    table[b * NCB + t] = s[t] - c;
    if (t == NCB - 1) tot[b] = s[t];
}

// phase B2: exclusive scan of bucket totals -> bucket start offsets
__global__ __launch_bounds__(256) void scanb2_kernel(const int* __restrict__ tot,
                                                     int* __restrict__ bstart,
                                                     int* __restrict__ ptr, int E) {
    __shared__ int s[256];
    int t = threadIdx.x;
    int v = (t < NBUCK) ? tot[t] : 0;
    s[t] = v;
    __syncthreads();
#pragma unroll
    for (int off = 1; off < 256; off <<= 1) {
        int u = (t >= off) ? s[t - off] : 0;
        __syncthreads();
        s[t] += u;
        __syncthreads();
    }
    if (t < NBUCK) bstart[t] = s[t] - v;
    if (t == 0) {
        bstart[NBUCK] = E;
        ptr[N_NODES] = E;
    }
}

// phase C: scatter packed (src | dlow<<17) into contiguous per-(bucket,block) runs
__global__ __launch_bounds__(256) void bin_kernel(const int* __restrict__ src,
                                                  const int* __restrict__ dst,
                                                  const int* __restrict__ table,
                                                  const int* __restrict__ bstart,
                                                  unsigned* __restrict__ binned, int E, int chunk) {
    __shared__ int cur[NBUCK];
    int blk = blockIdx.x;
    for (int i = threadIdx.x; i < NBUCK; i += 256) cur[i] = bstart[i] + table[i * NCB + blk];
    __syncthreads();
    int e0 = blk * chunk;
    int e1 = min(E, e0 + chunk);
    for (int e = e0 + threadIdx.x; e < e1; e += 256) {
        int d = dst[e];
        int b = d >> 9;
        int pos = atomicAdd(&cur[b], 1);  // LDS atomic
        binned[pos] = (unsigned)src[e] | ((unsigned)(d & 511) << 17);
    }
}

// phase D: one block per bucket — per-node degree (LDS), scan, write ptr + sorted
__global__ __launch_bounds__(256) void place_kernel(const unsigned* __restrict__ binned,
                                                    const int* __restrict__ bstart,
                                                    int* __restrict__ ptr,
                                                    int* __restrict__ sorted, int N) {
    __shared__ int deg[512];
    __shared__ int cur[512];
    __shared__ int ssum[256];
    int b = blockIdx.x, t = threadIdx.x;
    int start = bstart[b], end = bstart[b + 1];
    deg[t] = 0;
    deg[t + 256] = 0;
    __syncthreads();
    for (int i = start + t; i < end; i += 256) atomicAdd(&deg[binned[i] >> 17], 1);
    __syncthreads();
    int a = deg[2 * t], c = deg[2 * t + 1];
    int s2 = a + c;
    ssum[t] = s2;
    __syncthreads();
#pragma unroll
    for (int off = 1; off < 256; off <<= 1) {
        int u = (t >= off) ? ssum[t - off] : 0;
        __syncthreads();
        ssum[t] += u;
        __syncthreads();
    }
    int excl2 = ssum[t] - s2;
    cur[2 * t] = excl2;
    cur[2 * t + 1] = excl2 + a;
    int n0 = b * 512 + 2 * t;
    if (n0 < N) ptr[n0] = start + excl2;
    if (n0 + 1 < N) ptr[n0 + 1] = start + excl2 + a;
    __syncthreads();
    for (int i = start + t; i < end; i += 256) {
        unsigned p = binned[i];
        int dl = p >> 17;
        int pos = start + atomicAdd(&cur[dl], 1);  // LDS atomic
        sorted[pos] = (int)(p & 0x1FFFF);
    }
}

// ================= fp32 -> bf16 convert =================
__global__ __launch_bounds__(256) void convert_bf_kernel(const float* __restrict__ in,
                                                         unsigned short* __restrict__ out,
                                                         int n4) {
    int i = blockIdx.x * blockDim.x + threadIdx.x;
    if (i >= n4) return;
    float4 v = ((const float4*)in)[i];
    ushort4 o;
    o.x = f2bf(v.x); o.y = f2bf(v.y); o.z = f2bf(v.z); o.w = f2bf(v.w);
    ((ushort4*)out)[i] = o;
}

// ================= weight pack into MFMA B-fragment order =================
// Bpack chunk index ((s*8 + t)*64 + lane), 8 bf16 each:
//   b_frag[j] = Wcat[k = s*32 + (lane>>4)*8 + j][n = t*16 + (lane&15)]
template <int K>
__global__ __launch_bounds__(256) void pack_w_kernel(const float* __restrict__ Wn,
                                                     const float* __restrict__ Ws,
                                                     unsigned short* __restrict__ Bpack) {
    constexpr int KT = 2 * K;
    constexpr int TOT = (KT / 32) * 8 * 64;
    int idx = blockIdx.x * blockDim.x + threadIdx.x;
    if (idx >= TOT) return;
    int s = idx >> 9;
    int rem = idx & 511;
    int t = rem >> 6;
    int lane = rem & 63;
    int quad = lane >> 4;
    int n = t * 16 + (lane & 15);
    unsigned short v[8];
#pragma unroll
    for (int j = 0; j < 8; ++j) {
        int k = s * 32 + quad * 8 + j;
        float w = (k < K) ? Wn[(size_t)k * HID + n] : Ws[(size_t)(k - K) * HID + n];
        v[j] = f2bf(w);
    }
    *(short8*)(Bpack + (size_t)idx * 8) = *(short8*)v;
}

// ================= gather + mean (bf16 in/out, fp32 accum) =================
template <int C>
__global__ __launch_bounds__(256) void gather_mean(const int* __restrict__ ptr,
                                                   const int* __restrict__ srcs,
                                                   const unsigned short* __restrict__ feat,
                                                   unsigned short* __restrict__ mean, int N) {
    int w = (blockIdx.x * blockDim.x + threadIdx.x) >> 6;
    if (w >= N) return;
    int lane = threadIdx.x & 63;
    int s0 = ptr[w], s1 = ptr[w + 1];
    constexpr int V = C / 64;
    float acc0[V] = {}, acc1[V] = {};
    int j = s0;
    for (; j + 2 <= s1; j += 2) {
        const unsigned short* rA = feat + (size_t)srcs[j] * C;
        const unsigned short* rB = feat + (size_t)srcs[j + 1] * C;
        if (V == 1) {
            acc0[0] += bf2f(rA[lane]);
            acc1[0] += bf2f(rB[lane]);
        } else {
            uint a = *(const uint*)(rA + lane * 2);
            uint b = *(const uint*)(rB + lane * 2);
            acc0[0] += bf2f((unsigned short)(a & 0xffff));
            acc0[1] += bf2f((unsigned short)(a >> 16));
            acc1[0] += bf2f((unsigned short)(b & 0xffff));
            acc1[1] += bf2f((unsigned short)(b >> 16));
        }
    }
    if (j < s1) {
        const unsigned short* rA = feat + (size_t)srcs[j] * C;
        if (V == 1) {
            acc0[0] += bf2f(rA[lane]);
        } else {
            uint a = *(const uint*)(rA + lane * 2);
            acc0[0] += bf2f((unsigned short)(a & 0xffff));
            acc0[1] += bf2f((unsigned short)(a >> 16));
        }
    }
    float inv = (s1 > s0) ? 1.0f / (float)(s1 - s0) : 0.0f;
    if (V == 1) {
        mean[(size_t)w * C + lane] = f2bf((acc0[0] + acc1[0]) * inv);
    } else {
        unsigned short lo16 = f2bf((acc0[0] + acc1[0]) * inv);
        unsigned short hi16 = f2bf((acc0[1] + acc1[1]) * inv);
        *(uint*)(mean + (size_t)w * C + lane * 2) = (uint)lo16 | ((uint)hi16 << 16);
    }
}

// ================= MFMA SAGE GEMM: relu([mean|h] @ [Wn;Ws] + b) =================
template <int KT, bool FUSE_FC>
__global__ __launch_bounds__(256) void sage_gemm_mfma(const unsigned short* __restrict__ meanb,
                                                      const unsigned short* __restrict__ hb,
                                                      const unsigned short* __restrict__ Bpack,
                                                      const float* __restrict__ bias,
                                                      const float* __restrict__ fcw,
                                                      const float* __restrict__ fcb,
                                                      unsigned short* __restrict__ outb,
                                                      float* __restrict__ outf, int N) {
    constexpr int KH = KT / 2;
    constexpr int LDA = KT + 8;
    __shared__ unsigned short As[64 * LDA];
    const int t = threadIdx.x;
    const int row0 = blockIdx.x * 64;

    constexpr int SEGS = KT / 8;
    for (int c = t; c < 64 * SEGS; c += 256) {
        int r = c / SEGS, seg = c % SEGS;
        int rsrc = row0 + r;
        if (rsrc >= N) rsrc = N - 1;
        const unsigned short* srcp = (seg < SEGS / 2)
                                         ? meanb + (size_t)rsrc * KH + seg * 8
                                         : hb + (size_t)rsrc * KH + (seg - SEGS / 2) * 8;
        *(uint4*)&As[r * LDA + seg * 8] = *(const uint4*)srcp;
    }
    __syncthreads();

    const int lane = t & 63;
    const int wave = t >> 6;
    const int quad = lane >> 4;
    const int lo = lane & 15;

    floatx4 acc[8];
#pragma unroll
    for (int i = 0; i < 8; ++i)
#pragma unroll
        for (int r = 0; r < 4; ++r) acc[i][r] = 0.0f;

    const unsigned short* abase = &As[(wave * 16 + lo) * LDA + quad * 8];
#pragma unroll
    for (int s = 0; s < KT / 32; ++s) {
        short8 a = *(const short8*)(abase + s * 32);
        const short8* bp = (const short8*)Bpack + (size_t)(s * 8) * 64 + lane;
#pragma unroll
        for (int tt = 0; tt < 8; ++tt) {
            short8 b = bp[tt * 64];
            acc[tt] = __builtin_amdgcn_mfma_f32_16x16x32_bf16(a, b, acc[tt], 0, 0, 0);
        }
    }

    if (!FUSE_FC) {
#pragma unroll
        for (int tt = 0; tt < 8; ++tt) {
            int col = tt * 16 + lo;
            float bv = bias[col];
#pragma unroll
            for (int r = 0; r < 4; ++r) {
                int row = row0 + wave * 16 + quad * 4 + r;
                if (row < N) {
                    float v = fmaxf(acc[tt][r] + bv, 0.0f);
                    outb[(size_t)row * HID + col] = f2bf(v);
                }
            }
        }
    } else {
        float o0[4] = {}, o1[4] = {};
#pragma unroll
        for (int tt = 0; tt < 8; ++tt) {
            int col = tt * 16 + lo;
            float bv = bias[col];
            float w0 = fcw[col * 2 + 0];
            float w1 = fcw[col * 2 + 1];
#pragma unroll
            for (int r = 0; r < 4; ++r) {
                float v = fmaxf(acc[tt][r] + bv, 0.0f);
                o0[r] += v * w0;
                o1[r] += v * w1;
            }
        }
#pragma unroll
        for (int r = 0; r < 4; ++r) {
#pragma unroll
            for (int m = 8; m >= 1; m >>= 1) {
                o0[r] += __shfl_xor(o0[r], m, 16);
                o1[r] += __shfl_xor(o1[r], m, 16);
            }
        }
        if (lo == 0) {
#pragma unroll
            for (int r = 0; r < 4; ++r) {
                int row = row0 + wave * 16 + quad * 4 + r;
                if (row < N) {
                    outf[(size_t)row * 2 + 0] = o0[r] + fcb[0];
                    outf[(size_t)row * 2 + 1] = o1[r] + fcb[1];
                }
            }
        }
    }
}

extern "C" void kernel_launch(void* const* d_in, const int* in_sizes, int n_in,
                              void* d_out, int out_size, void* d_ws, size_t ws_size,
                              hipStream_t stream) {
    const float* x   = (const float*)d_in[0];
    const int*   ei  = (const int*)d_in[1];
    const float* Wn0 = (const float*)d_in[2];
    const float* Ws0 = (const float*)d_in[3];
    const float* b0  = (const float*)d_in[4];
    const float* Wn1 = (const float*)d_in[5];
    const float* Ws1 = (const float*)d_in[6];
    const float* b1  = (const float*)d_in[7];
    const float* fcw = (const float*)d_in[8];
    const float* fcb = (const float*)d_in[9];
    float* out = (float*)d_out;

    const int E = in_sizes[1] / 2;
    const int* src = ei;
    const int* dst = ei + E;
    const int N = N_NODES;
    const int chunk = (E + NCB - 1) / NCB;

    // workspace layout
    char* ws = (char*)d_ws;
    size_t off = 0;
    int* table  = (int*)(ws + off); off += (size_t)NBUCK * NCB * 4;       // 200 KB
    int* tot    = (int*)(ws + off); off += 4096;
    int* bstart = (int*)(ws + off); off += 4096;
    int* ptr    = (int*)(ws + off); off += (size_t)(N + 1) * 4 + 60; off &= ~(size_t)63;
    unsigned* binned = (unsigned*)(ws + off); off += (size_t)E * 4;       // 6.4 MB
    int* sorted = (int*)(ws + off); off += (size_t)E * 4;                 // 6.4 MB
    off = (off + 255) & ~(size_t)255;
    unsigned short* x_bf   = (unsigned short*)(ws + off); off += (size_t)N * IN_CH * 2;
    unsigned short* mean0  = (unsigned short*)(ws + off); off += (size_t)N * IN_CH * 2;
    unsigned short* h1_bf  = (unsigned short*)(ws + off); off += (size_t)N * HID * 2;
    unsigned short* mean1  = (unsigned short*)(ws + off); off += (size_t)N * HID * 2;
    unsigned short* Bpack0 = (unsigned short*)(ws + off); off += (size_t)(2 * IN_CH / 32) * 8 * 64 * 8 * 2;
    unsigned short* Bpack1 = (unsigned short*)(ws + off); off += (size_t)(2 * HID / 32) * 8 * 64 * 8 * 2;

    // ---- CSR build (binned counting sort, zero global atomics) ----
    hist_kernel<<<NCB, 256, 0, stream>>>(dst, table, E, chunk);
    scanb1_kernel<<<NBUCK, 256, 0, stream>>>(table, tot);
    scanb2_kernel<<<1, 256, 0, stream>>>(tot, bstart, ptr, E);
    bin_kernel<<<NCB, 256, 0, stream>>>(src, dst, table, bstart, binned, E, chunk);
    place_kernel<<<NBUCK, 256, 0, stream>>>(binned, bstart, ptr, sorted, N);

    // ---- conversions / weight packing ----
    {
        int n4 = N * IN_CH / 4;
        convert_bf_kernel<<<(n4 + 255) / 256, 256, 0, stream>>>(x, x_bf, n4);
    }
    pack_w_kernel<IN_CH><<<((2 * IN_CH / 32) * 8 * 64 + 255) / 256, 256, 0, stream>>>(Wn0, Ws0, Bpack0);
    pack_w_kernel<HID><<<((2 * HID / 32) * 8 * 64 + 255) / 256, 256, 0, stream>>>(Wn1, Ws1, Bpack1);

    // ---- layer 0 ----
    gather_mean<IN_CH><<<(N * 64 + 255) / 256, 256, 0, stream>>>(ptr, sorted, x_bf, mean0, N);
    sage_gemm_mfma<2 * IN_CH, false><<<(N + 63) / 64, 256, 0, stream>>>(
        mean0, x_bf, Bpack0, b0, nullptr, nullptr, h1_bf, nullptr, N);

    // ---- layer 1 + fused fc ----
    gather_mean<HID><<<(N * 64 + 255) / 256, 256, 0, stream>>>(ptr, sorted, h1_bf, mean1, N);
    sage_gemm_mfma<2 * HID, true><<<(N + 63) / 64, 256, 0, stream>>>(
        mean1, h1_bf, Bpack1, b1, fcw, fcb, nullptr, out, N);
}

// Round 5
// 293.074 us; speedup vs baseline: 4.7855x; 1.2520x over previous
//
#include <hip/hip_runtime.h>

#define N_NODES 100000
#define IN_CH 64
#define HID 128
#define NBUCK ((N_NODES + 511) >> 9)   // 196 coarse buckets of 512 nodes
#define NCB 256                        // edge-chunk blocks for hist/bin

typedef short short8 __attribute__((ext_vector_type(8)));
typedef float floatx4 __attribute__((ext_vector_type(4)));

__device__ __forceinline__ unsigned short f2bf(float f) {
    unsigned u = __builtin_bit_cast(unsigned, f);
    u += 0x7fffu + ((u >> 16) & 1u);  // RNE
    return (unsigned short)(u >> 16);
}
__device__ __forceinline__ float bf2f(unsigned short h) {
    unsigned u = ((unsigned)h) << 16;
    return __builtin_bit_cast(float, u);
}

// ================= binned counting-sort CSR build (no global atomics) =================

__global__ __launch_bounds__(256) void hist_kernel(const int* __restrict__ dst,
                                                   int* __restrict__ table, int E, int chunk) {
    __shared__ int h[NBUCK];
    for (int i = threadIdx.x; i < NBUCK; i += 256) h[i] = 0;
    __syncthreads();
    int e0 = blockIdx.x * chunk;
    int e1 = min(E, e0 + chunk);
    for (int e = e0 + threadIdx.x; e < e1; e += 256) atomicAdd(&h[dst[e] >> 9], 1);
    __syncthreads();
    for (int i = threadIdx.x; i < NBUCK; i += 256) table[i * NCB + blockIdx.x] = h[i];
}

__global__ __launch_bounds__(256) void scanb1_kernel(int* __restrict__ table,
                                                     int* __restrict__ tot) {
    __shared__ int s[NCB];
    int b = blockIdx.x, t = threadIdx.x;
    int c = table[b * NCB + t];
    s[t] = c;
    __syncthreads();
#pragma unroll
    for (int off = 1; off < NCB; off <<= 1) {
        int v = (t >= off) ? s[t - off] : 0;
        __syncthreads();
        s[t] += v;
        __syncthreads();
    }
    table[b * NCB + t] = s[t] - c;
    if (t == NCB - 1) tot[b] = s[t];
}

__global__ __launch_bounds__(256) void scanb2_kernel(const int* __restrict__ tot,
                                                     int* __restrict__ bstart,
                                                     int* __restrict__ ptr, int E) {
    __shared__ int s[256];
    int t = threadIdx.x;
    int v = (t < NBUCK) ? tot[t] : 0;
    s[t] = v;
    __syncthreads();
#pragma unroll
    for (int off = 1; off < 256; off <<= 1) {
        int u = (t >= off) ? s[t - off] : 0;
        __syncthreads();
        s[t] += u;
        __syncthreads();
    }
    if (t < NBUCK) bstart[t] = s[t] - v;
    if (t == 0) {
        bstart[NBUCK] = E;
        ptr[N_NODES] = E;
    }
}

__global__ __launch_bounds__(256) void bin_kernel(const int* __restrict__ src,
                                                  const int* __restrict__ dst,
                                                  const int* __restrict__ table,
                                                  const int* __restrict__ bstart,
                                                  unsigned* __restrict__ binned, int E, int chunk) {
    __shared__ int cur[NBUCK];
    int blk = blockIdx.x;
    for (int i = threadIdx.x; i < NBUCK; i += 256) cur[i] = bstart[i] + table[i * NCB + blk];
    __syncthreads();
    int e0 = blk * chunk;
    int e1 = min(E, e0 + chunk);
    for (int e = e0 + threadIdx.x; e < e1; e += 256) {
        int d = dst[e];
        int b = d >> 9;
        int pos = atomicAdd(&cur[b], 1);  // LDS atomic
        binned[pos] = (unsigned)src[e] | ((unsigned)(d & 511) << 17);
    }
}

__global__ __launch_bounds__(256) void place_kernel(const unsigned* __restrict__ binned,
                                                    const int* __restrict__ bstart,
                                                    int* __restrict__ ptr,
                                                    int* __restrict__ sorted, int N) {
    __shared__ int deg[512];
    __shared__ int cur[512];
    __shared__ int ssum[256];
    int b = blockIdx.x, t = threadIdx.x;
    int start = bstart[b], end = bstart[b + 1];
    deg[t] = 0;
    deg[t + 256] = 0;
    __syncthreads();
    for (int i = start + t; i < end; i += 256) atomicAdd(&deg[binned[i] >> 17], 1);
    __syncthreads();
    int a = deg[2 * t], c = deg[2 * t + 1];
    int s2 = a + c;
    ssum[t] = s2;
    __syncthreads();
#pragma unroll
    for (int off = 1; off < 256; off <<= 1) {
        int u = (t >= off) ? ssum[t - off] : 0;
        __syncthreads();
        ssum[t] += u;
        __syncthreads();
    }
    int excl2 = ssum[t] - s2;
    cur[2 * t] = excl2;
    cur[2 * t + 1] = excl2 + a;
    int n0 = b * 512 + 2 * t;
    if (n0 < N) ptr[n0] = start + excl2;
    if (n0 + 1 < N) ptr[n0 + 1] = start + excl2 + a;
    __syncthreads();
    for (int i = start + t; i < end; i += 256) {
        unsigned p = binned[i];
        int dl = p >> 17;
        int pos = start + atomicAdd(&cur[dl], 1);  // LDS atomic
        sorted[pos] = (int)(p & 0x1FFFF);
    }
}

// ================= fp32 -> bf16 convert =================
__global__ __launch_bounds__(256) void convert_bf_kernel(const float* __restrict__ in,
                                                         unsigned short* __restrict__ out,
                                                         int n4) {
    int i = blockIdx.x * blockDim.x + threadIdx.x;
    if (i >= n4) return;
    float4 v = ((const float4*)in)[i];
    ushort4 o;
    o.x = f2bf(v.x); o.y = f2bf(v.y); o.z = f2bf(v.z); o.w = f2bf(v.w);
    ((ushort4*)out)[i] = o;
}

// ================= weight pack into MFMA B-fragment order =================
template <int K>
__global__ __launch_bounds__(256) void pack_w_kernel(const float* __restrict__ Wn,
                                                     const float* __restrict__ Ws,
                                                     unsigned short* __restrict__ Bpack) {
    constexpr int KT = 2 * K;
    constexpr int TOT = (KT / 32) * 8 * 64;
    int idx = blockIdx.x * blockDim.x + threadIdx.x;
    if (idx >= TOT) return;
    int s = idx >> 9;
    int rem = idx & 511;
    int t = rem >> 6;
    int lane = rem & 63;
    int quad = lane >> 4;
    int n = t * 16 + (lane & 15);
    unsigned short v[8];
#pragma unroll
    for (int j = 0; j < 8; ++j) {
        int k = s * 32 + quad * 8 + j;
        float w = (k < K) ? Wn[(size_t)k * HID + n] : Ws[(size_t)(k - K) * HID + n];
        v[j] = f2bf(w);
    }
    *(short8*)(Bpack + (size_t)idx * 8) = *(short8*)v;
}

// ================= gather + mean v2 =================
// LPR = C/8 lanes cover one row with dwordx4 (8 bf16 / lane); G = 64/LPR edges
// per load-slot, 2 slots in flight (unroll 2). Cross-group shfl_xor reduction,
// lanes < LPR write the 16B-aligned mean row.
template <int C>
__global__ __launch_bounds__(256) void gather_mean(const int* __restrict__ ptr,
                                                   const int* __restrict__ srcs,
                                                   const unsigned short* __restrict__ feat,
                                                   unsigned short* __restrict__ mean, int N) {
    constexpr int LPR = C / 8;    // lanes per row: 8 (C=64) / 16 (C=128)
    constexpr int G = 64 / LPR;   // edges per slot: 8 / 4
    int w = (blockIdx.x * blockDim.x + threadIdx.x) >> 6;
    if (w >= N) return;
    int lane = threadIdx.x & 63;
    int g = lane / LPR;           // edge slot within group
    int l = lane % LPR;           // 16B segment within row
    int s0 = ptr[w], s1 = ptr[w + 1];

    float acc[8] = {};
    for (int j = s0; j < s1; j += 2 * G) {
        int jj0 = j + g;
        int jj1 = j + G + g;
        uint4 v0 = {0, 0, 0, 0}, v1 = {0, 0, 0, 0};
        if (jj0 < s1) v0 = *(const uint4*)(feat + (size_t)srcs[jj0] * C + l * 8);
        if (jj1 < s1) v1 = *(const uint4*)(feat + (size_t)srcs[jj1] * C + l * 8);
        const uint* p0 = (const uint*)&v0;
        const uint* p1 = (const uint*)&v1;
#pragma unroll
        for (int u = 0; u < 4; ++u) {
            acc[2 * u + 0] += bf2f((unsigned short)(p0[u] & 0xffff)) +
                              bf2f((unsigned short)(p1[u] & 0xffff));
            acc[2 * u + 1] += bf2f((unsigned short)(p0[u] >> 16)) +
                              bf2f((unsigned short)(p1[u] >> 16));
        }
    }
    // reduce across the G edge-slots (lanes differing in bits >= log2(LPR))
#pragma unroll
    for (int m = LPR; m < 64; m <<= 1) {
#pragma unroll
        for (int u = 0; u < 8; ++u) acc[u] += __shfl_xor(acc[u], m, 64);
    }
    if (g == 0) {
        float inv = (s1 > s0) ? 1.0f / (float)(s1 - s0) : 0.0f;
        unsigned short o[8];
#pragma unroll
        for (int u = 0; u < 8; ++u) o[u] = f2bf(acc[u] * inv);
        *(uint4*)(mean + (size_t)w * C + l * 8) = *(const uint4*)o;
    }
}

// ================= MFMA SAGE GEMM: relu([mean|h] @ [Wn;Ws] + b) =================
template <int KT, bool FUSE_FC>
__global__ __launch_bounds__(256) void sage_gemm_mfma(const unsigned short* __restrict__ meanb,
                                                      const unsigned short* __restrict__ hb,
                                                      const unsigned short* __restrict__ Bpack,
                                                      const float* __restrict__ bias,
                                                      const float* __restrict__ fcw,
                                                      const float* __restrict__ fcb,
                                                      unsigned short* __restrict__ outb,
                                                      float* __restrict__ outf, int N) {
    constexpr int KH = KT / 2;
    constexpr int LDA = KT + 8;
    __shared__ unsigned short As[64 * LDA];
    const int t = threadIdx.x;
    const int row0 = blockIdx.x * 64;

    constexpr int SEGS = KT / 8;
    for (int c = t; c < 64 * SEGS; c += 256) {
        int r = c / SEGS, seg = c % SEGS;
        int rsrc = row0 + r;
        if (rsrc >= N) rsrc = N - 1;
        const unsigned short* srcp = (seg < SEGS / 2)
                                         ? meanb + (size_t)rsrc * KH + seg * 8
                                         : hb + (size_t)rsrc * KH + (seg - SEGS / 2) * 8;
        *(uint4*)&As[r * LDA + seg * 8] = *(const uint4*)srcp;
    }
    __syncthreads();

    const int lane = t & 63;
    const int wave = t >> 6;
    const int quad = lane >> 4;
    const int lo = lane & 15;

    floatx4 acc[8];
#pragma unroll
    for (int i = 0; i < 8; ++i)
#pragma unroll
        for (int r = 0; r < 4; ++r) acc[i][r] = 0.0f;

    const unsigned short* abase = &As[(wave * 16 + lo) * LDA + quad * 8];
#pragma unroll
    for (int s = 0; s < KT / 32; ++s) {
        short8 a = *(const short8*)(abase + s * 32);
        const short8* bp = (const short8*)Bpack + (size_t)(s * 8) * 64 + lane;
#pragma unroll
        for (int tt = 0; tt < 8; ++tt) {
            short8 b = bp[tt * 64];
            acc[tt] = __builtin_amdgcn_mfma_f32_16x16x32_bf16(a, b, acc[tt], 0, 0, 0);
        }
    }

    if (!FUSE_FC) {
#pragma unroll
        for (int tt = 0; tt < 8; ++tt) {
            int col = tt * 16 + lo;
            float bv = bias[col];
#pragma unroll
            for (int r = 0; r < 4; ++r) {
                int row = row0 + wave * 16 + quad * 4 + r;
                if (row < N) {
                    float v = fmaxf(acc[tt][r] + bv, 0.0f);
                    outb[(size_t)row * HID + col] = f2bf(v);
                }
            }
        }
    } else {
        float o0[4] = {}, o1[4] = {};
#pragma unroll
        for (int tt = 0; tt < 8; ++tt) {
            int col = tt * 16 + lo;
            float bv = bias[col];
            float w0 = fcw[col * 2 + 0];
            float w1 = fcw[col * 2 + 1];
#pragma unroll
            for (int r = 0; r < 4; ++r) {
                float v = fmaxf(acc[tt][r] + bv, 0.0f);
                o0[r] += v * w0;
                o1[r] += v * w1;
            }
        }
#pragma unroll
        for (int r = 0; r < 4; ++r) {
#pragma unroll
            for (int m = 8; m >= 1; m >>= 1) {
                o0[r] += __shfl_xor(o0[r], m, 16);
                o1[r] += __shfl_xor(o1[r], m, 16);
            }
        }
        if (lo == 0) {
#pragma unroll
            for (int r = 0; r < 4; ++r) {
                int row = row0 + wave * 16 + quad * 4 + r;
                if (row < N) {
                    outf[(size_t)row * 2 + 0] = o0[r] + fcb[0];
                    outf[(size_t)row * 2 + 1] = o1[r] + fcb[1];
                }
            }
        }
    }
}

extern "C" void kernel_launch(void* const* d_in, const int* in_sizes, int n_in,
                              void* d_out, int out_size, void* d_ws, size_t ws_size,
                              hipStream_t stream) {
    const float* x   = (const float*)d_in[0];
    const int*   ei  = (const int*)d_in[1];
    const float* Wn0 = (const float*)d_in[2];
    const float* Ws0 = (const float*)d_in[3];
    const float* b0  = (const float*)d_in[4];
    const float* Wn1 = (const float*)d_in[5];
    const float* Ws1 = (const float*)d_in[6];
    const float* b1  = (const float*)d_in[7];
    const float* fcw = (const float*)d_in[8];
    const float* fcb = (const float*)d_in[9];
    float* out = (float*)d_out;

    const int E = in_sizes[1] / 2;
    const int* src = ei;
    const int* dst = ei + E;
    const int N = N_NODES;
    const int chunk = (E + NCB - 1) / NCB;

    // workspace layout
    char* ws = (char*)d_ws;
    size_t off = 0;
    int* table  = (int*)(ws + off); off += (size_t)NBUCK * NCB * 4;
    int* tot    = (int*)(ws + off); off += 4096;
    int* bstart = (int*)(ws + off); off += 4096;
    int* ptr    = (int*)(ws + off); off += (size_t)(N + 1) * 4 + 60; off &= ~(size_t)63;
    unsigned* binned = (unsigned*)(ws + off); off += (size_t)E * 4;
    int* sorted = (int*)(ws + off); off += (size_t)E * 4;
    off = (off + 255) & ~(size_t)255;
    unsigned short* x_bf   = (unsigned short*)(ws + off); off += (size_t)N * IN_CH * 2;
    unsigned short* mean0  = (unsigned short*)(ws + off); off += (size_t)N * IN_CH * 2;
    unsigned short* h1_bf  = (unsigned short*)(ws + off); off += (size_t)N * HID * 2;
    unsigned short* mean1  = (unsigned short*)(ws + off); off += (size_t)N * HID * 2;
    unsigned short* Bpack0 = (unsigned short*)(ws + off); off += (size_t)(2 * IN_CH / 32) * 8 * 64 * 8 * 2;
    unsigned short* Bpack1 = (unsigned short*)(ws + off); off += (size_t)(2 * HID / 32) * 8 * 64 * 8 * 2;

    // ---- CSR build (binned counting sort, zero global atomics) ----
    hist_kernel<<<NCB, 256, 0, stream>>>(dst, table, E, chunk);
    scanb1_kernel<<<NBUCK, 256, 0, stream>>>(table, tot);
    scanb2_kernel<<<1, 256, 0, stream>>>(tot, bstart, ptr, E);
    bin_kernel<<<NCB, 256, 0, stream>>>(src, dst, table, bstart, binned, E, chunk);
    place_kernel<<<NBUCK, 256, 0, stream>>>(binned, bstart, ptr, sorted, N);

    // ---- conversions / weight packing ----
    {
        int n4 = N * IN_CH / 4;
        convert_bf_kernel<<<(n4 + 255) / 256, 256, 0, stream>>>(x, x_bf, n4);
    }
    pack_w_kernel<IN_CH><<<((2 * IN_CH / 32) * 8 * 64 + 255) / 256, 256, 0, stream>>>(Wn0, Ws0, Bpack0);
    pack_w_kernel<HID><<<((2 * HID / 32) * 8 * 64 + 255) / 256, 256, 0, stream>>>(Wn1, Ws1, Bpack1);

    // ---- layer 0 ----
    gather_mean<IN_CH><<<(N * 64 + 255) / 256, 256, 0, stream>>>(ptr, sorted, x_bf, mean0, N);
    sage_gemm_mfma<2 * IN_CH, false><<<(N + 63) / 64, 256, 0, stream>>>(
        mean0, x_bf, Bpack0, b0, nullptr, nullptr, h1_bf, nullptr, N);

    // ---- layer 1 + fused fc ----
    gather_mean<HID><<<(N * 64 + 255) / 256, 256, 0, stream>>>(ptr, sorted, h1_bf, mean1, N);
    sage_gemm_mfma<2 * HID, true><<<(N + 63) / 64, 256, 0, stream>>>(
        mean1, h1_bf, Bpack1, b1, fcw, fcb, nullptr, out, N);
}

// Round 6
// 292.240 us; speedup vs baseline: 4.7991x; 1.0029x over previous
//
#include <hip/hip_runtime.h>

#define N_NODES 100000
#define IN_CH 64
#define HID 128
#define NBUCK ((N_NODES + 511) >> 9)   // 196 coarse buckets of 512 nodes
#define NCB 256                        // edge-chunk blocks for hist/bin

typedef short short8 __attribute__((ext_vector_type(8)));
typedef float floatx4 __attribute__((ext_vector_type(4)));

__device__ __forceinline__ unsigned short f2bf(float f) {
    unsigned u = __builtin_bit_cast(unsigned, f);
    u += 0x7fffu + ((u >> 16) & 1u);  // RNE
    return (unsigned short)(u >> 16);
}
__device__ __forceinline__ float bf2f(unsigned short h) {
    unsigned u = ((unsigned)h) << 16;
    return __builtin_bit_cast(float, u);
}
__device__ __forceinline__ float bflo(uint p) {  // low bf16 of a packed pair
    return __builtin_bit_cast(float, p << 16);
}
__device__ __forceinline__ float bfhi(uint p) {  // high bf16 of a packed pair
    return __builtin_bit_cast(float, p & 0xffff0000u);
}

// ================= binned counting-sort CSR build (no global atomics) =================

__global__ __launch_bounds__(256) void hist_kernel(const int* __restrict__ dst,
                                                   int* __restrict__ table, int E, int chunk) {
    __shared__ int h[NBUCK];
    for (int i = threadIdx.x; i < NBUCK; i += 256) h[i] = 0;
    __syncthreads();
    int e0 = blockIdx.x * chunk;
    int e1 = min(E, e0 + chunk);
    for (int e = e0 + threadIdx.x; e < e1; e += 256) atomicAdd(&h[dst[e] >> 9], 1);
    __syncthreads();
    for (int i = threadIdx.x; i < NBUCK; i += 256) table[i * NCB + blockIdx.x] = h[i];
}

__global__ __launch_bounds__(256) void scanb1_kernel(int* __restrict__ table,
                                                     int* __restrict__ tot) {
    __shared__ int s[NCB];
    int b = blockIdx.x, t = threadIdx.x;
    int c = table[b * NCB + t];
    s[t] = c;
    __syncthreads();
#pragma unroll
    for (int off = 1; off < NCB; off <<= 1) {
        int v = (t >= off) ? s[t - off] : 0;
        __syncthreads();
        s[t] += v;
        __syncthreads();
    }
    table[b * NCB + t] = s[t] - c;
    if (t == NCB - 1) tot[b] = s[t];
}

__global__ __launch_bounds__(256) void scanb2_kernel(const int* __restrict__ tot,
                                                     int* __restrict__ bstart,
                                                     int* __restrict__ ptr, int E) {
    __shared__ int s[256];
    int t = threadIdx.x;
    int v = (t < NBUCK) ? tot[t] : 0;
    s[t] = v;
    __syncthreads();
#pragma unroll
    for (int off = 1; off < 256; off <<= 1) {
        int u = (t >= off) ? s[t - off] : 0;
        __syncthreads();
        s[t] += u;
        __syncthreads();
    }
    if (t < NBUCK) bstart[t] = s[t] - v;
    if (t == 0) {
        bstart[NBUCK] = E;
        ptr[N_NODES] = E;
    }
}

__global__ __launch_bounds__(256) void bin_kernel(const int* __restrict__ src,
                                                  const int* __restrict__ dst,
                                                  const int* __restrict__ table,
                                                  const int* __restrict__ bstart,
                                                  unsigned* __restrict__ binned, int E, int chunk) {
    __shared__ int cur[NBUCK];
    int blk = blockIdx.x;
    for (int i = threadIdx.x; i < NBUCK; i += 256) cur[i] = bstart[i] + table[i * NCB + blk];
    __syncthreads();
    int e0 = blk * chunk;
    int e1 = min(E, e0 + chunk);
    for (int e = e0 + threadIdx.x; e < e1; e += 256) {
        int d = dst[e];
        int b = d >> 9;
        int pos = atomicAdd(&cur[b], 1);  // LDS atomic
        binned[pos] = (unsigned)src[e] | ((unsigned)(d & 511) << 17);
    }
}

__global__ __launch_bounds__(256) void place_kernel(const unsigned* __restrict__ binned,
                                                    const int* __restrict__ bstart,
                                                    int* __restrict__ ptr,
                                                    int* __restrict__ sorted, int N) {
    __shared__ int deg[512];
    __shared__ int cur[512];
    __shared__ int ssum[256];
    int b = blockIdx.x, t = threadIdx.x;
    int start = bstart[b], end = bstart[b + 1];
    deg[t] = 0;
    deg[t + 256] = 0;
    __syncthreads();
    for (int i = start + t; i < end; i += 256) atomicAdd(&deg[binned[i] >> 17], 1);
    __syncthreads();
    int a = deg[2 * t], c = deg[2 * t + 1];
    int s2 = a + c;
    ssum[t] = s2;
    __syncthreads();
#pragma unroll
    for (int off = 1; off < 256; off <<= 1) {
        int u = (t >= off) ? ssum[t - off] : 0;
        __syncthreads();
        ssum[t] += u;
        __syncthreads();
    }
    int excl2 = ssum[t] - s2;
    cur[2 * t] = excl2;
    cur[2 * t + 1] = excl2 + a;
    int n0 = b * 512 + 2 * t;
    if (n0 < N) ptr[n0] = start + excl2;
    if (n0 + 1 < N) ptr[n0 + 1] = start + excl2 + a;
    __syncthreads();
    for (int i = start + t; i < end; i += 256) {
        unsigned p = binned[i];
        int dl = p >> 17;
        int pos = start + atomicAdd(&cur[dl], 1);  // LDS atomic
        sorted[pos] = (int)(p & 0x1FFFF);
    }
}

// ================= fp32 -> bf16 convert =================
__global__ __launch_bounds__(256) void convert_bf_kernel(const float* __restrict__ in,
                                                         unsigned short* __restrict__ out,
                                                         int n4) {
    int i = blockIdx.x * blockDim.x + threadIdx.x;
    if (i >= n4) return;
    float4 v = ((const float4*)in)[i];
    ushort4 o;
    o.x = f2bf(v.x); o.y = f2bf(v.y); o.z = f2bf(v.z); o.w = f2bf(v.w);
    ((ushort4*)out)[i] = o;
}

// ================= weight pack into MFMA B-fragment order =================
template <int K>
__global__ __launch_bounds__(256) void pack_w_kernel(const float* __restrict__ Wn,
                                                     const float* __restrict__ Ws,
                                                     unsigned short* __restrict__ Bpack) {
    constexpr int KT = 2 * K;
    constexpr int TOT = (KT / 32) * 8 * 64;
    int idx = blockIdx.x * blockDim.x + threadIdx.x;
    if (idx >= TOT) return;
    int s = idx >> 9;
    int rem = idx & 511;
    int t = rem >> 6;
    int lane = rem & 63;
    int quad = lane >> 4;
    int n = t * 16 + (lane & 15);
    unsigned short v[8];
#pragma unroll
    for (int j = 0; j < 8; ++j) {
        int k = s * 32 + quad * 8 + j;
        float w = (k < K) ? Wn[(size_t)k * HID + n] : Ws[(size_t)(k - K) * HID + n];
        v[j] = f2bf(w);
    }
    *(short8*)(Bpack + (size_t)idx * 8) = *(short8*)v;
}

// ================= gather + mean v3 =================
// LPR = C/8 lanes cover one row with dwordx4 (8 bf16 / lane); G = 64/LPR edges
// per load-slot, 4 slots in flight. Tree-sum into acc; cross-group shfl_xor
// reduction; lanes < LPR write the 16B mean row.
template <int C>
__global__ __launch_bounds__(256) void gather_mean(const int* __restrict__ ptr,
                                                   const int* __restrict__ srcs,
                                                   const unsigned short* __restrict__ feat,
                                                   unsigned short* __restrict__ mean, int N) {
    constexpr int LPR = C / 8;    // lanes per row: 8 (C=64) / 16 (C=128)
    constexpr int G = 64 / LPR;   // edges per slot: 8 / 4
    int w = (blockIdx.x * blockDim.x + threadIdx.x) >> 6;
    if (w >= N) return;
    int lane = threadIdx.x & 63;
    int g = lane / LPR;           // edge slot within group
    int l = lane % LPR;           // 16B segment within row
    int s0 = ptr[w], s1 = ptr[w + 1];

    float acc[8] = {};
    for (int j = s0; j < s1; j += 4 * G) {
        uint4 v[4];
#pragma unroll
        for (int q = 0; q < 4; ++q) {
            int jj = j + q * G + g;
            uint4 t = {0, 0, 0, 0};
            if (jj < s1) t = *(const uint4*)(feat + (size_t)srcs[jj] * C + l * 8);
            v[q] = t;
        }
        const uint* p0 = (const uint*)&v[0];
        const uint* p1 = (const uint*)&v[1];
        const uint* p2 = (const uint*)&v[2];
        const uint* p3 = (const uint*)&v[3];
#pragma unroll
        for (int u = 0; u < 4; ++u) {
            float lo01 = bflo(p0[u]) + bflo(p1[u]);
            float lo23 = bflo(p2[u]) + bflo(p3[u]);
            float hi01 = bfhi(p0[u]) + bfhi(p1[u]);
            float hi23 = bfhi(p2[u]) + bfhi(p3[u]);
            acc[2 * u + 0] += lo01 + lo23;
            acc[2 * u + 1] += hi01 + hi23;
        }
    }
    // reduce across the G edge-slots (lanes differing in bits >= log2(LPR))
#pragma unroll
    for (int m = LPR; m < 64; m <<= 1) {
#pragma unroll
        for (int u = 0; u < 8; ++u) acc[u] += __shfl_xor(acc[u], m, 64);
    }
    if (g == 0) {
        float inv = (s1 > s0) ? 1.0f / (float)(s1 - s0) : 0.0f;
        unsigned short o[8];
#pragma unroll
        for (int u = 0; u < 8; ++u) o[u] = f2bf(acc[u] * inv);
        *(uint4*)(mean + (size_t)w * C + l * 8) = *(const uint4*)o;
    }
}

// ================= MFMA SAGE GEMM: relu([mean|h] @ [Wn;Ws] + b) =================
template <int KT, bool FUSE_FC>
__global__ __launch_bounds__(256) void sage_gemm_mfma(const unsigned short* __restrict__ meanb,
                                                      const unsigned short* __restrict__ hb,
                                                      const unsigned short* __restrict__ Bpack,
                                                      const float* __restrict__ bias,
                                                      const float* __restrict__ fcw,
                                                      const float* __restrict__ fcb,
                                                      unsigned short* __restrict__ outb,
                                                      float* __restrict__ outf, int N) {
    constexpr int KH = KT / 2;
    constexpr int LDA = KT + 8;
    __shared__ unsigned short As[64 * LDA];
    const int t = threadIdx.x;
    const int row0 = blockIdx.x * 64;

    constexpr int SEGS = KT / 8;
    for (int c = t; c < 64 * SEGS; c += 256) {
        int r = c / SEGS, seg = c % SEGS;
        int rsrc = row0 + r;
        if (rsrc >= N) rsrc = N - 1;
        const unsigned short* srcp = (seg < SEGS / 2)
                                         ? meanb + (size_t)rsrc * KH + seg * 8
                                         : hb + (size_t)rsrc * KH + (seg - SEGS / 2) * 8;
        *(uint4*)&As[r * LDA + seg * 8] = *(const uint4*)srcp;
    }
    __syncthreads();

    const int lane = t & 63;
    const int wave = t >> 6;
    const int quad = lane >> 4;
    const int lo = lane & 15;

    floatx4 acc[8];
#pragma unroll
    for (int i = 0; i < 8; ++i)
#pragma unroll
        for (int r = 0; r < 4; ++r) acc[i][r] = 0.0f;

    const unsigned short* abase = &As[(wave * 16 + lo) * LDA + quad * 8];
#pragma unroll
    for (int s = 0; s < KT / 32; ++s) {
        short8 a = *(const short8*)(abase + s * 32);
        const short8* bp = (const short8*)Bpack + (size_t)(s * 8) * 64 + lane;
#pragma unroll
        for (int tt = 0; tt < 8; ++tt) {
            short8 b = bp[tt * 64];
            acc[tt] = __builtin_amdgcn_mfma_f32_16x16x32_bf16(a, b, acc[tt], 0, 0, 0);
        }
    }

    if (!FUSE_FC) {
#pragma unroll
        for (int tt = 0; tt < 8; ++tt) {
            int col = tt * 16 + lo;
            float bv = bias[col];
#pragma unroll
            for (int r = 0; r < 4; ++r) {
                int row = row0 + wave * 16 + quad * 4 + r;
                if (row < N) {
                    float v = fmaxf(acc[tt][r] + bv, 0.0f);
                    outb[(size_t)row * HID + col] = f2bf(v);
                }
            }
        }
    } else {
        float o0[4] = {}, o1[4] = {};
#pragma unroll
        for (int tt = 0; tt < 8; ++tt) {
            int col = tt * 16 + lo;
            float bv = bias[col];
            float w0 = fcw[col * 2 + 0];
            float w1 = fcw[col * 2 + 1];
#pragma unroll
            for (int r = 0; r < 4; ++r) {
                float v = fmaxf(acc[tt][r] + bv, 0.0f);
                o0[r] += v * w0;
                o1[r] += v * w1;
            }
        }
#pragma unroll
        for (int r = 0; r < 4; ++r) {
#pragma unroll
            for (int m = 8; m >= 1; m >>= 1) {
                o0[r] += __shfl_xor(o0[r], m, 16);
                o1[r] += __shfl_xor(o1[r], m, 16);
            }
        }
        if (lo == 0) {
#pragma unroll
            for (int r = 0; r < 4; ++r) {
                int row = row0 + wave * 16 + quad * 4 + r;
                if (row < N) {
                    outf[(size_t)row * 2 + 0] = o0[r] + fcb[0];
                    outf[(size_t)row * 2 + 1] = o1[r] + fcb[1];
                }
            }
        }
    }
}

extern "C" void kernel_launch(void* const* d_in, const int* in_sizes, int n_in,
                              void* d_out, int out_size, void* d_ws, size_t ws_size,
                              hipStream_t stream) {
    const float* x   = (const float*)d_in[0];
    const int*   ei  = (const int*)d_in[1];
    const float* Wn0 = (const float*)d_in[2];
    const float* Ws0 = (const float*)d_in[3];
    const float* b0  = (const float*)d_in[4];
    const float* Wn1 = (const float*)d_in[5];
    const float* Ws1 = (const float*)d_in[6];
    const float* b1  = (const float*)d_in[7];
    const float* fcw = (const float*)d_in[8];
    const float* fcb = (const float*)d_in[9];
    float* out = (float*)d_out;

    const int E = in_sizes[1] / 2;
    const int* src = ei;
    const int* dst = ei + E;
    const int N = N_NODES;
    const int chunk = (E + NCB - 1) / NCB;

    // workspace layout
    char* ws = (char*)d_ws;
    size_t off = 0;
    int* table  = (int*)(ws + off); off += (size_t)NBUCK * NCB * 4;
    int* tot    = (int*)(ws + off); off += 4096;
    int* bstart = (int*)(ws + off); off += 4096;
    int* ptr    = (int*)(ws + off); off += (size_t)(N + 1) * 4 + 60; off &= ~(size_t)63;
    unsigned* binned = (unsigned*)(ws + off); off += (size_t)E * 4;
    int* sorted = (int*)(ws + off); off += (size_t)E * 4;
    off = (off + 255) & ~(size_t)255;
    unsigned short* x_bf   = (unsigned short*)(ws + off); off += (size_t)N * IN_CH * 2;
    unsigned short* mean0  = (unsigned short*)(ws + off); off += (size_t)N * IN_CH * 2;
    unsigned short* h1_bf  = (unsigned short*)(ws + off); off += (size_t)N * HID * 2;
    unsigned short* mean1  = (unsigned short*)(ws + off); off += (size_t)N * HID * 2;
    unsigned short* Bpack0 = (unsigned short*)(ws + off); off += (size_t)(2 * IN_CH / 32) * 8 * 64 * 8 * 2;
    unsigned short* Bpack1 = (unsigned short*)(ws + off); off += (size_t)(2 * HID / 32) * 8 * 64 * 8 * 2;

    // ---- CSR build (binned counting sort, zero global atomics) ----
    hist_kernel<<<NCB, 256, 0, stream>>>(dst, table, E, chunk);
    scanb1_kernel<<<NBUCK, 256, 0, stream>>>(table, tot);
    scanb2_kernel<<<1, 256, 0, stream>>>(tot, bstart, ptr, E);
    bin_kernel<<<NCB, 256, 0, stream>>>(src, dst, table, bstart, binned, E, chunk);
    place_kernel<<<NBUCK, 256, 0, stream>>>(binned, bstart, ptr, sorted, N);

    // ---- conversions / weight packing ----
    {
        int n4 = N * IN_CH / 4;
        convert_bf_kernel<<<(n4 + 255) / 256, 256, 0, stream>>>(x, x_bf, n4);
    }
    pack_w_kernel<IN_CH><<<((2 * IN_CH / 32) * 8 * 64 + 255) / 256, 256, 0, stream>>>(Wn0, Ws0, Bpack0);
    pack_w_kernel<HID><<<((2 * HID / 32) * 8 * 64 + 255) / 256, 256, 0, stream>>>(Wn1, Ws1, Bpack1);

    // ---- layer 0 ----
    gather_mean<IN_CH><<<(N * 64 + 255) / 256, 256, 0, stream>>>(ptr, sorted, x_bf, mean0, N);
    sage_gemm_mfma<2 * IN_CH, false><<<(N + 63) / 64, 256, 0, stream>>>(
        mean0, x_bf, Bpack0, b0, nullptr, nullptr, h1_bf, nullptr, N);

    // ---- layer 1 + fused fc ----
    gather_mean<HID><<<(N * 64 + 255) / 256, 256, 0, stream>>>(ptr, sorted, h1_bf, mean1, N);
    sage_gemm_mfma<2 * HID, true><<<(N + 63) / 64, 256, 0, stream>>>(
        mean1, h1_bf, Bpack1, b1, fcw, fcb, nullptr, out, N);
}

// Round 7
// 283.491 us; speedup vs baseline: 4.9472x; 1.0309x over previous
//
#include <hip/hip_runtime.h>

#define N_NODES 100000
#define IN_CH 64
#define HID 128
#define NBUCK ((N_NODES + 511) >> 9)   // 196 coarse buckets of 512 nodes
#define NCB 256                        // edge-chunk blocks for hist/bin

typedef short short8 __attribute__((ext_vector_type(8)));
typedef float floatx4 __attribute__((ext_vector_type(4)));

__device__ __forceinline__ unsigned short f2bf(float f) {
    unsigned u = __builtin_bit_cast(unsigned, f);
    u += 0x7fffu + ((u >> 16) & 1u);  // RNE
    return (unsigned short)(u >> 16);
}
__device__ __forceinline__ float bf2f(unsigned short h) {
    unsigned u = ((unsigned)h) << 16;
    return __builtin_bit_cast(float, u);
}
__device__ __forceinline__ float bflo(uint p) {  // low bf16 of a packed pair
    return __builtin_bit_cast(float, p << 16);
}
__device__ __forceinline__ float bfhi(uint p) {  // high bf16 of a packed pair
    return __builtin_bit_cast(float, p & 0xffff0000u);
}

// ================= binned counting-sort CSR build (no global atomics) =================

__global__ __launch_bounds__(256) void hist_kernel(const int* __restrict__ dst,
                                                   int* __restrict__ table, int E, int chunk) {
    __shared__ int h[NBUCK];
    for (int i = threadIdx.x; i < NBUCK; i += 256) h[i] = 0;
    __syncthreads();
    int e0 = blockIdx.x * chunk;
    int e1 = min(E, e0 + chunk);
    for (int e = e0 + threadIdx.x; e < e1; e += 256) atomicAdd(&h[dst[e] >> 9], 1);
    __syncthreads();
    for (int i = threadIdx.x; i < NBUCK; i += 256) table[i * NCB + blockIdx.x] = h[i];
}

__global__ __launch_bounds__(256) void scanb1_kernel(int* __restrict__ table,
                                                     int* __restrict__ tot) {
    __shared__ int s[NCB];
    int b = blockIdx.x, t = threadIdx.x;
    int c = table[b * NCB + t];
    s[t] = c;
    __syncthreads();
#pragma unroll
    for (int off = 1; off < NCB; off <<= 1) {
        int v = (t >= off) ? s[t - off] : 0;
        __syncthreads();
        s[t] += v;
        __syncthreads();
    }
    table[b * NCB + t] = s[t] - c;
    if (t == NCB - 1) tot[b] = s[t];
}

__global__ __launch_bounds__(256) void scanb2_kernel(const int* __restrict__ tot,
                                                     int* __restrict__ bstart,
                                                     int* __restrict__ ptr, int E) {
    __shared__ int s[256];
    int t = threadIdx.x;
    int v = (t < NBUCK) ? tot[t] : 0;
    s[t] = v;
    __syncthreads();
#pragma unroll
    for (int off = 1; off < 256; off <<= 1) {
        int u = (t >= off) ? s[t - off] : 0;
        __syncthreads();
        s[t] += u;
        __syncthreads();
    }
    if (t < NBUCK) bstart[t] = s[t] - v;
    if (t == 0) {
        bstart[NBUCK] = E;
        ptr[N_NODES] = E;
    }
}

__global__ __launch_bounds__(256) void bin_kernel(const int* __restrict__ src,
                                                  const int* __restrict__ dst,
                                                  const int* __restrict__ table,
                                                  const int* __restrict__ bstart,
                                                  unsigned* __restrict__ binned, int E, int chunk) {
    __shared__ int cur[NBUCK];
    int blk = blockIdx.x;
    for (int i = threadIdx.x; i < NBUCK; i += 256) cur[i] = bstart[i] + table[i * NCB + blk];
    __syncthreads();
    int e0 = blk * chunk;
    int e1 = min(E, e0 + chunk);
    for (int e = e0 + threadIdx.x; e < e1; e += 256) {
        int d = dst[e];
        int b = d >> 9;
        int pos = atomicAdd(&cur[b], 1);  // LDS atomic
        binned[pos] = (unsigned)src[e] | ((unsigned)(d & 511) << 17);
    }
}

__global__ __launch_bounds__(256) void place_kernel(const unsigned* __restrict__ binned,
                                                    const int* __restrict__ bstart,
                                                    int* __restrict__ ptr,
                                                    int* __restrict__ sorted, int N) {
    __shared__ int deg[512];
    __shared__ int cur[512];
    __shared__ int ssum[256];
    int b = blockIdx.x, t = threadIdx.x;
    int start = bstart[b], end = bstart[b + 1];
    deg[t] = 0;
    deg[t + 256] = 0;
    __syncthreads();
    for (int i = start + t; i < end; i += 256) atomicAdd(&deg[binned[i] >> 17], 1);
    __syncthreads();
    int a = deg[2 * t], c = deg[2 * t + 1];
    int s2 = a + c;
    ssum[t] = s2;
    __syncthreads();
#pragma unroll
    for (int off = 1; off < 256; off <<= 1) {
        int u = (t >= off) ? ssum[t - off] : 0;
        __syncthreads();
        ssum[t] += u;
        __syncthreads();
    }
    int excl2 = ssum[t] - s2;
    cur[2 * t] = excl2;
    cur[2 * t + 1] = excl2 + a;
    int n0 = b * 512 + 2 * t;
    if (n0 < N) ptr[n0] = start + excl2;
    if (n0 + 1 < N) ptr[n0 + 1] = start + excl2 + a;
    __syncthreads();
    for (int i = start + t; i < end; i += 256) {
        unsigned p = binned[i];
        int dl = p >> 17;
        int pos = start + atomicAdd(&cur[dl], 1);  // LDS atomic
        sorted[pos] = (int)(p & 0x1FFFF);
    }
}

// ================= fp32 -> bf16 convert =================
__global__ __launch_bounds__(256) void convert_bf_kernel(const float* __restrict__ in,
                                                         unsigned short* __restrict__ out,
                                                         int n4) {
    int i = blockIdx.x * blockDim.x + threadIdx.x;
    if (i >= n4) return;
    float4 v = ((const float4*)in)[i];
    ushort4 o;
    o.x = f2bf(v.x); o.y = f2bf(v.y); o.z = f2bf(v.z); o.w = f2bf(v.w);
    ((ushort4*)out)[i] = o;
}

// ================= weight pack into MFMA B-fragment order =================
template <int K>
__global__ __launch_bounds__(256) void pack_w_kernel(const float* __restrict__ Wn,
                                                     const float* __restrict__ Ws,
                                                     unsigned short* __restrict__ Bpack) {
    constexpr int KT = 2 * K;
    constexpr int TOT = (KT / 32) * 8 * 64;
    int idx = blockIdx.x * blockDim.x + threadIdx.x;
    if (idx >= TOT) return;
    int s = idx >> 9;
    int rem = idx & 511;
    int t = rem >> 6;
    int lane = rem & 63;
    int quad = lane >> 4;
    int n = t * 16 + (lane & 15);
    unsigned short v[8];
#pragma unroll
    for (int j = 0; j < 8; ++j) {
        int k = s * 32 + quad * 8 + j;
        float w = (k < K) ? Wn[(size_t)k * HID + n] : Ws[(size_t)(k - K) * HID + n];
        v[j] = f2bf(w);
    }
    *(short8*)(Bpack + (size_t)idx * 8) = *(short8*)v;
}

// ================= gather + mean v4 =================
// LPR = C/8 lanes cover one row with dwordx4 (8 bf16/lane); G = 64/LPR edges
// per slot, 4 slots in flight. Neighbor indices batch-loaded 64-at-a-time into
// a register and distributed via __shfl (no narrow index loads). float2
// accumulators -> v_pk_add_f32.
template <int C>
__global__ __launch_bounds__(256) void gather_mean(const int* __restrict__ ptr,
                                                   const int* __restrict__ srcs,
                                                   const unsigned short* __restrict__ feat,
                                                   unsigned short* __restrict__ mean, int N) {
    constexpr int LPR = C / 8;    // lanes per row: 8 (C=64) / 16 (C=128)
    constexpr int G = 64 / LPR;   // edges per slot: 8 / 4
    int w = (blockIdx.x * blockDim.x + threadIdx.x) >> 6;
    if (w >= N) return;
    int lane = threadIdx.x & 63;
    int g = lane / LPR;           // edge slot within group
    int l = lane % LPR;           // 16B segment within row
    int s0 = ptr[w], s1 = ptr[w + 1];
    int deg = s1 - s0;

    float2 acc2[4];
#pragma unroll
    for (int u = 0; u < 4; ++u) acc2[u] = make_float2(0.0f, 0.0f);

    for (int jb = 0; jb < deg; jb += 64) {
        int idxreg = (s0 + jb + lane < s1) ? srcs[s0 + jb + lane] : 0;
        int bend = min(64, deg - jb);
        for (int o0 = 0; o0 < bend; o0 += 4 * G) {
            uint4 v[4];
#pragma unroll
            for (int q = 0; q < 4; ++q) {
                int o = o0 + q * G + g;
                int idx = __shfl(idxreg, o);
                uint4 t = {0, 0, 0, 0};
                if (o < bend) t = *(const uint4*)(feat + (size_t)idx * C + l * 8);
                v[q] = t;
            }
            const uint* p0 = (const uint*)&v[0];
            const uint* p1 = (const uint*)&v[1];
            const uint* p2 = (const uint*)&v[2];
            const uint* p3 = (const uint*)&v[3];
#pragma unroll
            for (int u = 0; u < 4; ++u) {
                float2 a01 = make_float2(bflo(p0[u]) , bfhi(p0[u]));
                float2 a1  = make_float2(bflo(p1[u]) , bfhi(p1[u]));
                float2 a23 = make_float2(bflo(p2[u]) , bfhi(p2[u]));
                float2 a3  = make_float2(bflo(p3[u]) , bfhi(p3[u]));
                a01.x += a1.x;  a01.y += a1.y;
                a23.x += a3.x;  a23.y += a3.y;
                a01.x += a23.x; a01.y += a23.y;
                acc2[u].x += a01.x;
                acc2[u].y += a01.y;
            }
        }
    }
    // reduce across the G edge-slots (lanes differing in bits >= log2(LPR))
#pragma unroll
    for (int m = LPR; m < 64; m <<= 1) {
#pragma unroll
        for (int u = 0; u < 4; ++u) {
            acc2[u].x += __shfl_xor(acc2[u].x, m, 64);
            acc2[u].y += __shfl_xor(acc2[u].y, m, 64);
        }
    }
    if (g == 0) {
        float inv = (deg > 0) ? 1.0f / (float)deg : 0.0f;
        unsigned short o[8];
#pragma unroll
        for (int u = 0; u < 4; ++u) {
            o[2 * u + 0] = f2bf(acc2[u].x * inv);
            o[2 * u + 1] = f2bf(acc2[u].y * inv);
        }
        *(uint4*)(mean + (size_t)w * C + l * 8) = *(const uint4*)o;
    }
}

// ================= MFMA SAGE GEMM: relu([mean|h] @ [Wn;Ws] + b) =================
template <int KT, bool FUSE_FC>
__global__ __launch_bounds__(256) void sage_gemm_mfma(const unsigned short* __restrict__ meanb,
                                                      const unsigned short* __restrict__ hb,
                                                      const unsigned short* __restrict__ Bpack,
                                                      const float* __restrict__ bias,
                                                      const float* __restrict__ fcw,
                                                      const float* __restrict__ fcb,
                                                      unsigned short* __restrict__ outb,
                                                      float* __restrict__ outf, int N) {
    constexpr int KH = KT / 2;
    constexpr int LDA = KT + 8;
    __shared__ unsigned short As[64 * LDA];
    const int t = threadIdx.x;
    const int row0 = blockIdx.x * 64;

    constexpr int SEGS = KT / 8;
    for (int c = t; c < 64 * SEGS; c += 256) {
        int r = c / SEGS, seg = c % SEGS;
        int rsrc = row0 + r;
        if (rsrc >= N) rsrc = N - 1;
        const unsigned short* srcp = (seg < SEGS / 2)
                                         ? meanb + (size_t)rsrc * KH + seg * 8
                                         : hb + (size_t)rsrc * KH + (seg - SEGS / 2) * 8;
        *(uint4*)&As[r * LDA + seg * 8] = *(const uint4*)srcp;
    }
    __syncthreads();

    const int lane = t & 63;
    const int wave = t >> 6;
    const int quad = lane >> 4;
    const int lo = lane & 15;

    floatx4 acc[8];
#pragma unroll
    for (int i = 0; i < 8; ++i)
#pragma unroll
        for (int r = 0; r < 4; ++r) acc[i][r] = 0.0f;

    const unsigned short* abase = &As[(wave * 16 + lo) * LDA + quad * 8];
#pragma unroll
    for (int s = 0; s < KT / 32; ++s) {
        short8 a = *(const short8*)(abase + s * 32);
        const short8* bp = (const short8*)Bpack + (size_t)(s * 8) * 64 + lane;
#pragma unroll
        for (int tt = 0; tt < 8; ++tt) {
            short8 b = bp[tt * 64];
            acc[tt] = __builtin_amdgcn_mfma_f32_16x16x32_bf16(a, b, acc[tt], 0, 0, 0);
        }
    }

    if (!FUSE_FC) {
#pragma unroll
        for (int tt = 0; tt < 8; ++tt) {
            int col = tt * 16 + lo;
            float bv = bias[col];
#pragma unroll
            for (int r = 0; r < 4; ++r) {
                int row = row0 + wave * 16 + quad * 4 + r;
                if (row < N) {
                    float v = fmaxf(acc[tt][r] + bv, 0.0f);
                    outb[(size_t)row * HID + col] = f2bf(v);
                }
            }
        }
    } else {
        float o0[4] = {}, o1[4] = {};
#pragma unroll
        for (int tt = 0; tt < 8; ++tt) {
            int col = tt * 16 + lo;
            float bv = bias[col];
            float w0 = fcw[col * 2 + 0];
            float w1 = fcw[col * 2 + 1];
#pragma unroll
            for (int r = 0; r < 4; ++r) {
                float v = fmaxf(acc[tt][r] + bv, 0.0f);
                o0[r] += v * w0;
                o1[r] += v * w1;
            }
        }
#pragma unroll
        for (int r = 0; r < 4; ++r) {
#pragma unroll
            for (int m = 8; m >= 1; m >>= 1) {
                o0[r] += __shfl_xor(o0[r], m, 16);
                o1[r] += __shfl_xor(o1[r], m, 16);
            }
        }
        if (lo == 0) {
#pragma unroll
            for (int r = 0; r < 4; ++r) {
                int row = row0 + wave * 16 + quad * 4 + r;
                if (row < N) {
                    outf[(size_t)row * 2 + 0] = o0[r] + fcb[0];
                    outf[(size_t)row * 2 + 1] = o1[r] + fcb[1];
                }
            }
        }
    }
}

extern "C" void kernel_launch(void* const* d_in, const int* in_sizes, int n_in,
                              void* d_out, int out_size, void* d_ws, size_t ws_size,
                              hipStream_t stream) {
    const float* x   = (const float*)d_in[0];
    const int*   ei  = (const int*)d_in[1];
    const float* Wn0 = (const float*)d_in[2];
    const float* Ws0 = (const float*)d_in[3];
    const float* b0  = (const float*)d_in[4];
    const float* Wn1 = (const float*)d_in[5];
    const float* Ws1 = (const float*)d_in[6];
    const float* b1  = (const float*)d_in[7];
    const float* fcw = (const float*)d_in[8];
    const float* fcb = (const float*)d_in[9];
    float* out = (float*)d_out;

    const int E = in_sizes[1] / 2;
    const int* src = ei;
    const int* dst = ei + E;
    const int N = N_NODES;
    const int chunk = (E + NCB - 1) / NCB;

    // workspace layout
    char* ws = (char*)d_ws;
    size_t off = 0;
    int* table  = (int*)(ws + off); off += (size_t)NBUCK * NCB * 4;
    int* tot    = (int*)(ws + off); off += 4096;
    int* bstart = (int*)(ws + off); off += 4096;
    int* ptr    = (int*)(ws + off); off += (size_t)(N + 1) * 4 + 60; off &= ~(size_t)63;
    unsigned* binned = (unsigned*)(ws + off); off += (size_t)E * 4;
    int* sorted = (int*)(ws + off); off += (size_t)E * 4;
    off = (off + 255) & ~(size_t)255;
    unsigned short* x_bf   = (unsigned short*)(ws + off); off += (size_t)N * IN_CH * 2;
    unsigned short* mean0  = (unsigned short*)(ws + off); off += (size_t)N * IN_CH * 2;
    unsigned short* h1_bf  = (unsigned short*)(ws + off); off += (size_t)N * HID * 2;
    unsigned short* mean1  = (unsigned short*)(ws + off); off += (size_t)N * HID * 2;
    unsigned short* Bpack0 = (unsigned short*)(ws + off); off += (size_t)(2 * IN_CH / 32) * 8 * 64 * 8 * 2;
    unsigned short* Bpack1 = (unsigned short*)(ws + off); off += (size_t)(2 * HID / 32) * 8 * 64 * 8 * 2;

    // ---- CSR build (binned counting sort, zero global atomics) ----
    hist_kernel<<<NCB, 256, 0, stream>>>(dst, table, E, chunk);
    scanb1_kernel<<<NBUCK, 256, 0, stream>>>(table, tot);
    scanb2_kernel<<<1, 256, 0, stream>>>(tot, bstart, ptr, E);
    bin_kernel<<<NCB, 256, 0, stream>>>(src, dst, table, bstart, binned, E, chunk);
    place_kernel<<<NBUCK, 256, 0, stream>>>(binned, bstart, ptr, sorted, N);

    // ---- conversions / weight packing ----
    {
        int n4 = N * IN_CH / 4;
        convert_bf_kernel<<<(n4 + 255) / 256, 256, 0, stream>>>(x, x_bf, n4);
    }
    pack_w_kernel<IN_CH><<<((2 * IN_CH / 32) * 8 * 64 + 255) / 256, 256, 0, stream>>>(Wn0, Ws0, Bpack0);
    pack_w_kernel<HID><<<((2 * HID / 32) * 8 * 64 + 255) / 256, 256, 0, stream>>>(Wn1, Ws1, Bpack1);

    // ---- layer 0 ----
    gather_mean<IN_CH><<<(N * 64 + 255) / 256, 256, 0, stream>>>(ptr, sorted, x_bf, mean0, N);
    sage_gemm_mfma<2 * IN_CH, false><<<(N + 63) / 64, 256, 0, stream>>>(
        mean0, x_bf, Bpack0, b0, nullptr, nullptr, h1_bf, nullptr, N);

    // ---- layer 1 + fused fc ----
    gather_mean<HID><<<(N * 64 + 255) / 256, 256, 0, stream>>>(ptr, sorted, h1_bf, mean1, N);
    sage_gemm_mfma<2 * HID, true><<<(N + 63) / 64, 256, 0, stream>>>(
        mean1, h1_bf, Bpack1, b1, fcw, fcb, nullptr, out, N);
}

// Round 8
// 278.731 us; speedup vs baseline: 5.0317x; 1.0171x over previous
//
#include <hip/hip_runtime.h>

#define N_NODES 100000
#define IN_CH 64
#define HID 128
#define NBUCK ((N_NODES + 511) >> 9)   // 196 coarse buckets of 512 nodes
#define NCB 256                        // edge-chunk blocks for hist/bin

typedef short short8 __attribute__((ext_vector_type(8)));
typedef float floatx4 __attribute__((ext_vector_type(4)));

__device__ __forceinline__ unsigned short f2bf(float f) {
    unsigned u = __builtin_bit_cast(unsigned, f);
    u += 0x7fffu + ((u >> 16) & 1u);  // RNE
    return (unsigned short)(u >> 16);
}
__device__ __forceinline__ float bf2f(unsigned short h) {
    unsigned u = ((unsigned)h) << 16;
    return __builtin_bit_cast(float, u);
}

// acc += (sel ? hi : lo) bf16 half of packed pair p, via VOP3P dot2:
// D = S0.lo*S1.lo + S0.hi*S1.hi + S2.  ones = (1.0,0.0) or (0.0,1.0) in bf16.
__device__ __forceinline__ void dot2acc(float& acc, uint p, uint ones) {
    asm("v_dot2_f32_bf16 %0, %1, %2, %0" : "+v"(acc) : "v"(p), "v"(ones));
}
#define BF_ONE_LO 0x00003F80u
#define BF_ONE_HI 0x3F800000u

// ================= binned counting-sort CSR build (no global atomics) =================

__global__ __launch_bounds__(256) void hist_kernel(const int* __restrict__ dst,
                                                   int* __restrict__ table, int E, int chunk) {
    __shared__ int h[NBUCK];
    for (int i = threadIdx.x; i < NBUCK; i += 256) h[i] = 0;
    __syncthreads();
    int e0 = blockIdx.x * chunk;
    int e1 = min(E, e0 + chunk);
    for (int e = e0 + threadIdx.x; e < e1; e += 256) atomicAdd(&h[dst[e] >> 9], 1);
    __syncthreads();
    for (int i = threadIdx.x; i < NBUCK; i += 256) table[i * NCB + blockIdx.x] = h[i];
}

__global__ __launch_bounds__(256) void scanb1_kernel(int* __restrict__ table,
                                                     int* __restrict__ tot) {
    __shared__ int s[NCB];
    int b = blockIdx.x, t = threadIdx.x;
    int c = table[b * NCB + t];
    s[t] = c;
    __syncthreads();
#pragma unroll
    for (int off = 1; off < NCB; off <<= 1) {
        int v = (t >= off) ? s[t - off] : 0;
        __syncthreads();
        s[t] += v;
        __syncthreads();
    }
    table[b * NCB + t] = s[t] - c;
    if (t == NCB - 1) tot[b] = s[t];
}

__global__ __launch_bounds__(256) void scanb2_kernel(const int* __restrict__ tot,
                                                     int* __restrict__ bstart,
                                                     int* __restrict__ ptr, int E) {
    __shared__ int s[256];
    int t = threadIdx.x;
    int v = (t < NBUCK) ? tot[t] : 0;
    s[t] = v;
    __syncthreads();
#pragma unroll
    for (int off = 1; off < 256; off <<= 1) {
        int u = (t >= off) ? s[t - off] : 0;
        __syncthreads();
        s[t] += u;
        __syncthreads();
    }
    if (t < NBUCK) bstart[t] = s[t] - v;
    if (t == 0) {
        bstart[NBUCK] = E;
        ptr[N_NODES] = E;
    }
}

__global__ __launch_bounds__(256) void bin_kernel(const int* __restrict__ src,
                                                  const int* __restrict__ dst,
                                                  const int* __restrict__ table,
                                                  const int* __restrict__ bstart,
                                                  unsigned* __restrict__ binned, int E, int chunk) {
    __shared__ int cur[NBUCK];
    int blk = blockIdx.x;
    for (int i = threadIdx.x; i < NBUCK; i += 256) cur[i] = bstart[i] + table[i * NCB + blk];
    __syncthreads();
    int e0 = blk * chunk;
    int e1 = min(E, e0 + chunk);
    for (int e = e0 + threadIdx.x; e < e1; e += 256) {
        int d = dst[e];
        int b = d >> 9;
        int pos = atomicAdd(&cur[b], 1);  // LDS atomic
        binned[pos] = (unsigned)src[e] | ((unsigned)(d & 511) << 17);
    }
}

__global__ __launch_bounds__(256) void place_kernel(const unsigned* __restrict__ binned,
                                                    const int* __restrict__ bstart,
                                                    int* __restrict__ ptr,
                                                    int* __restrict__ sorted, int N) {
    __shared__ int deg[512];
    __shared__ int cur[512];
    __shared__ int ssum[256];
    int b = blockIdx.x, t = threadIdx.x;
    int start = bstart[b], end = bstart[b + 1];
    deg[t] = 0;
    deg[t + 256] = 0;
    __syncthreads();
    for (int i = start + t; i < end; i += 256) atomicAdd(&deg[binned[i] >> 17], 1);
    __syncthreads();
    int a = deg[2 * t], c = deg[2 * t + 1];
    int s2 = a + c;
    ssum[t] = s2;
    __syncthreads();
#pragma unroll
    for (int off = 1; off < 256; off <<= 1) {
        int u = (t >= off) ? ssum[t - off] : 0;
        __syncthreads();
        ssum[t] += u;
        __syncthreads();
    }
    int excl2 = ssum[t] - s2;
    cur[2 * t] = excl2;
    cur[2 * t + 1] = excl2 + a;
    int n0 = b * 512 + 2 * t;
    if (n0 < N) ptr[n0] = start + excl2;
    if (n0 + 1 < N) ptr[n0 + 1] = start + excl2 + a;
    __syncthreads();
    for (int i = start + t; i < end; i += 256) {
        unsigned p = binned[i];
        int dl = p >> 17;
        int pos = start + atomicAdd(&cur[dl], 1);  // LDS atomic
        sorted[pos] = (int)(p & 0x1FFFF);
    }
}

// ================= fused prep: bf16 convert of x + both weight packs =================
// Bpack chunk index ((s*8 + t)*64 + lane), 8 bf16 each:
//   b_frag[j] = Wcat[k = s*32 + (lane>>4)*8 + j][n = t*16 + (lane&15)]
template <int K>
__device__ __forceinline__ void pack_dev(const float* __restrict__ Wn,
                                         const float* __restrict__ Ws,
                                         unsigned short* __restrict__ Bpack, int idx) {
    int s = idx >> 9;
    int rem = idx & 511;
    int t = rem >> 6;
    int lane = rem & 63;
    int quad = lane >> 4;
    int n = t * 16 + (lane & 15);
    unsigned short v[8];
#pragma unroll
    for (int j = 0; j < 8; ++j) {
        int k = s * 32 + quad * 8 + j;
        float w = (k < K) ? Wn[(size_t)k * HID + n] : Ws[(size_t)(k - K) * HID + n];
        v[j] = f2bf(w);
    }
    *(short8*)(Bpack + (size_t)idx * 8) = *(short8*)v;
}

// blocks [0,8): pack0; [8,24): pack1; [24,...): x convert
__global__ __launch_bounds__(256) void prep_kernel(const float* __restrict__ x,
                                                   unsigned short* __restrict__ x_bf,
                                                   const float* __restrict__ Wn0,
                                                   const float* __restrict__ Ws0,
                                                   unsigned short* __restrict__ Bpack0,
                                                   const float* __restrict__ Wn1,
                                                   const float* __restrict__ Ws1,
                                                   unsigned short* __restrict__ Bpack1,
                                                   int n4) {
    int b = blockIdx.x;
    if (b < 8) {
        pack_dev<IN_CH>(Wn0, Ws0, Bpack0, b * 256 + threadIdx.x);
    } else if (b < 24) {
        pack_dev<HID>(Wn1, Ws1, Bpack1, (b - 8) * 256 + threadIdx.x);
    } else {
        int i = (b - 24) * 256 + threadIdx.x;
        if (i < n4) {
            float4 v = ((const float4*)x)[i];
            ushort4 o;
            o.x = f2bf(v.x); o.y = f2bf(v.y); o.z = f2bf(v.z); o.w = f2bf(v.w);
            ((ushort4*)x_bf)[i] = o;
        }
    }
}

// ================= gather + mean v5 (v_dot2_f32_bf16 accumulate) =================
// LPR = C/8 lanes cover one row with dwordx4 (8 bf16/lane); G = 64/LPR edges
// per slot, 4 slots in flight. Indices batch-loaded 64-wide into a register,
// distributed via __shfl. Full 4-slot blocks run unchecked; one checked tail.
template <int C>
__global__ __launch_bounds__(256) void gather_mean(const int* __restrict__ ptr,
                                                   const int* __restrict__ srcs,
                                                   const unsigned short* __restrict__ feat,
                                                   unsigned short* __restrict__ mean, int N) {
    constexpr int LPR = C / 8;    // lanes per row: 8 (C=64) / 16 (C=128)
    constexpr int G = 64 / LPR;   // edges per slot: 8 / 4
    constexpr int STEP = 4 * G;
    int w = (blockIdx.x * blockDim.x + threadIdx.x) >> 6;
    if (w >= N) return;
    int lane = threadIdx.x & 63;
    int g = lane / LPR;           // edge slot within group
    int l = lane % LPR;           // 16B segment within row
    int s0 = ptr[w], s1 = ptr[w + 1];
    int deg = s1 - s0;

    float2 acc2[4];
#pragma unroll
    for (int u = 0; u < 4; ++u) acc2[u] = make_float2(0.0f, 0.0f);

    for (int jb = 0; jb < deg; jb += 64) {
        int rem = min(64, deg - jb);
        int idxreg = (jb + lane < deg) ? srcs[s0 + jb + lane] : 0;
        int fullend = rem & ~(STEP - 1);
        int o0 = 0;
        for (; o0 < fullend; o0 += STEP) {   // unchecked full blocks
            uint4 v[4];
#pragma unroll
            for (int q = 0; q < 4; ++q) {
                int idx = __shfl(idxreg, o0 + q * G + g);
                v[q] = *(const uint4*)(feat + (size_t)idx * C + l * 8);
            }
            const uint* p0 = (const uint*)&v[0];
            const uint* p1 = (const uint*)&v[1];
            const uint* p2 = (const uint*)&v[2];
            const uint* p3 = (const uint*)&v[3];
#pragma unroll
            for (int u = 0; u < 4; ++u) {
                dot2acc(acc2[u].x, p0[u], BF_ONE_LO); dot2acc(acc2[u].y, p0[u], BF_ONE_HI);
                dot2acc(acc2[u].x, p1[u], BF_ONE_LO); dot2acc(acc2[u].y, p1[u], BF_ONE_HI);
                dot2acc(acc2[u].x, p2[u], BF_ONE_LO); dot2acc(acc2[u].y, p2[u], BF_ONE_HI);
                dot2acc(acc2[u].x, p3[u], BF_ONE_LO); dot2acc(acc2[u].y, p3[u], BF_ONE_HI);
            }
        }
        if (o0 < rem) {                      // checked tail block
            uint4 v[4];
#pragma unroll
            for (int q = 0; q < 4; ++q) {
                int o = o0 + q * G + g;
                int idx = __shfl(idxreg, o);
                uint4 t = {0, 0, 0, 0};
                if (o < rem) t = *(const uint4*)(feat + (size_t)idx * C + l * 8);
                v[q] = t;
            }
            const uint* p0 = (const uint*)&v[0];
            const uint* p1 = (const uint*)&v[1];
            const uint* p2 = (const uint*)&v[2];
            const uint* p3 = (const uint*)&v[3];
#pragma unroll
            for (int u = 0; u < 4; ++u) {
                dot2acc(acc2[u].x, p0[u], BF_ONE_LO); dot2acc(acc2[u].y, p0[u], BF_ONE_HI);
                dot2acc(acc2[u].x, p1[u], BF_ONE_LO); dot2acc(acc2[u].y, p1[u], BF_ONE_HI);
                dot2acc(acc2[u].x, p2[u], BF_ONE_LO); dot2acc(acc2[u].y, p2[u], BF_ONE_HI);
                dot2acc(acc2[u].x, p3[u], BF_ONE_LO); dot2acc(acc2[u].y, p3[u], BF_ONE_HI);
            }
        }
    }
    // reduce across the G edge-slots (lanes differing in bits >= log2(LPR))
#pragma unroll
    for (int m = LPR; m < 64; m <<= 1) {
#pragma unroll
        for (int u = 0; u < 4; ++u) {
            acc2[u].x += __shfl_xor(acc2[u].x, m, 64);
            acc2[u].y += __shfl_xor(acc2[u].y, m, 64);
        }
    }
    if (g == 0) {
        float inv = (deg > 0) ? 1.0f / (float)deg : 0.0f;
        unsigned short o[8];
#pragma unroll
        for (int u = 0; u < 4; ++u) {
            o[2 * u + 0] = f2bf(acc2[u].x * inv);
            o[2 * u + 1] = f2bf(acc2[u].y * inv);
        }
        *(uint4*)(mean + (size_t)w * C + l * 8) = *(const uint4*)o;
    }
}

// ================= MFMA SAGE GEMM: relu([mean|h] @ [Wn;Ws] + b) =================
template <int KT, bool FUSE_FC>
__global__ __launch_bounds__(256) void sage_gemm_mfma(const unsigned short* __restrict__ meanb,
                                                      const unsigned short* __restrict__ hb,
                                                      const unsigned short* __restrict__ Bpack,
                                                      const float* __restrict__ bias,
                                                      const float* __restrict__ fcw,
                                                      const float* __restrict__ fcb,
                                                      unsigned short* __restrict__ outb,
                                                      float* __restrict__ outf, int N) {
    constexpr int KH = KT / 2;
    constexpr int LDA = KT + 8;
    __shared__ unsigned short As[64 * LDA];
    const int t = threadIdx.x;
    const int row0 = blockIdx.x * 64;

    constexpr int SEGS = KT / 8;
    for (int c = t; c < 64 * SEGS; c += 256) {
        int r = c / SEGS, seg = c % SEGS;
        int rsrc = row0 + r;
        if (rsrc >= N) rsrc = N - 1;
        const unsigned short* srcp = (seg < SEGS / 2)
                                         ? meanb + (size_t)rsrc * KH + seg * 8
                                         : hb + (size_t)rsrc * KH + (seg - SEGS / 2) * 8;
        *(uint4*)&As[r * LDA + seg * 8] = *(const uint4*)srcp;
    }
    __syncthreads();

    const int lane = t & 63;
    const int wave = t >> 6;
    const int quad = lane >> 4;
    const int lo = lane & 15;

    floatx4 acc[8];
#pragma unroll
    for (int i = 0; i < 8; ++i)
#pragma unroll
        for (int r = 0; r < 4; ++r) acc[i][r] = 0.0f;

    const unsigned short* abase = &As[(wave * 16 + lo) * LDA + quad * 8];
#pragma unroll
    for (int s = 0; s < KT / 32; ++s) {
        short8 a = *(const short8*)(abase + s * 32);
        const short8* bp = (const short8*)Bpack + (size_t)(s * 8) * 64 + lane;
#pragma unroll
        for (int tt = 0; tt < 8; ++tt) {
            short8 b = bp[tt * 64];
            acc[tt] = __builtin_amdgcn_mfma_f32_16x16x32_bf16(a, b, acc[tt], 0, 0, 0);
        }
    }

    if (!FUSE_FC) {
#pragma unroll
        for (int tt = 0; tt < 8; ++tt) {
            int col = tt * 16 + lo;
            float bv = bias[col];
#pragma unroll
            for (int r = 0; r < 4; ++r) {
                int row = row0 + wave * 16 + quad * 4 + r;
                if (row < N) {
                    float v = fmaxf(acc[tt][r] + bv, 0.0f);
                    outb[(size_t)row * HID + col] = f2bf(v);
                }
            }
        }
    } else {
        float o0[4] = {}, o1[4] = {};
#pragma unroll
        for (int tt = 0; tt < 8; ++tt) {
            int col = tt * 16 + lo;
            float bv = bias[col];
            float w0 = fcw[col * 2 + 0];
            float w1 = fcw[col * 2 + 1];
#pragma unroll
            for (int r = 0; r < 4; ++r) {
                float v = fmaxf(acc[tt][r] + bv, 0.0f);
                o0[r] += v * w0;
                o1[r] += v * w1;
            }
        }
#pragma unroll
        for (int r = 0; r < 4; ++r) {
#pragma unroll
            for (int m = 8; m >= 1; m >>= 1) {
                o0[r] += __shfl_xor(o0[r], m, 16);
                o1[r] += __shfl_xor(o1[r], m, 16);
            }
        }
        if (lo == 0) {
#pragma unroll
            for (int r = 0; r < 4; ++r) {
                int row = row0 + wave * 16 + quad * 4 + r;
                if (row < N) {
                    outf[(size_t)row * 2 + 0] = o0[r] + fcb[0];
                    outf[(size_t)row * 2 + 1] = o1[r] + fcb[1];
                }
            }
        }
    }
}

extern "C" void kernel_launch(void* const* d_in, const int* in_sizes, int n_in,
                              void* d_out, int out_size, void* d_ws, size_t ws_size,
                              hipStream_t stream) {
    const float* x   = (const float*)d_in[0];
    const int*   ei  = (const int*)d_in[1];
    const float* Wn0 = (const float*)d_in[2];
    const float* Ws0 = (const float*)d_in[3];
    const float* b0  = (const float*)d_in[4];
    const float* Wn1 = (const float*)d_in[5];
    const float* Ws1 = (const float*)d_in[6];
    const float* b1  = (const float*)d_in[7];
    const float* fcw = (const float*)d_in[8];
    const float* fcb = (const float*)d_in[9];
    float* out = (float*)d_out;

    const int E = in_sizes[1] / 2;
    const int* src = ei;
    const int* dst = ei + E;
    const int N = N_NODES;
    const int chunk = (E + NCB - 1) / NCB;

    // workspace layout
    char* ws = (char*)d_ws;
    size_t off = 0;
    int* table  = (int*)(ws + off); off += (size_t)NBUCK * NCB * 4;
    int* tot    = (int*)(ws + off); off += 4096;
    int* bstart = (int*)(ws + off); off += 4096;
    int* ptr    = (int*)(ws + off); off += (size_t)(N + 1) * 4 + 60; off &= ~(size_t)63;
    unsigned* binned = (unsigned*)(ws + off); off += (size_t)E * 4;
    int* sorted = (int*)(ws + off); off += (size_t)E * 4;
    off = (off + 255) & ~(size_t)255;
    unsigned short* x_bf   = (unsigned short*)(ws + off); off += (size_t)N * IN_CH * 2;
    unsigned short* mean0  = (unsigned short*)(ws + off); off += (size_t)N * IN_CH * 2;
    unsigned short* h1_bf  = (unsigned short*)(ws + off); off += (size_t)N * HID * 2;
    unsigned short* mean1  = (unsigned short*)(ws + off); off += (size_t)N * HID * 2;
    unsigned short* Bpack0 = (unsigned short*)(ws + off); off += (size_t)(2 * IN_CH / 32) * 8 * 64 * 8 * 2;
    unsigned short* Bpack1 = (unsigned short*)(ws + off); off += (size_t)(2 * HID / 32) * 8 * 64 * 8 * 2;

    // ---- CSR build (binned counting sort, zero global atomics) ----
    hist_kernel<<<NCB, 256, 0, stream>>>(dst, table, E, chunk);
    scanb1_kernel<<<NBUCK, 256, 0, stream>>>(table, tot);
    scanb2_kernel<<<1, 256, 0, stream>>>(tot, bstart, ptr, E);
    bin_kernel<<<NCB, 256, 0, stream>>>(src, dst, table, bstart, binned, E, chunk);
    place_kernel<<<NBUCK, 256, 0, stream>>>(binned, bstart, ptr, sorted, N);

    // ---- fused conversions / weight packing ----
    {
        int n4 = N * IN_CH / 4;
        prep_kernel<<<24 + (n4 + 255) / 256, 256, 0, stream>>>(x, x_bf, Wn0, Ws0, Bpack0,
                                                               Wn1, Ws1, Bpack1, n4);
    }

    // ---- layer 0 ----
    gather_mean<IN_CH><<<(N * 64 + 255) / 256, 256, 0, stream>>>(ptr, sorted, x_bf, mean0, N);
    sage_gemm_mfma<2 * IN_CH, false><<<(N + 63) / 64, 256, 0, stream>>>(
        mean0, x_bf, Bpack0, b0, nullptr, nullptr, h1_bf, nullptr, N);

    // ---- layer 1 + fused fc ----
    gather_mean<HID><<<(N * 64 + 255) / 256, 256, 0, stream>>>(ptr, sorted, h1_bf, mean1, N);
    sage_gemm_mfma<2 * HID, true><<<(N + 63) / 64, 256, 0, stream>>>(
        mean1, h1_bf, Bpack1, b1, fcw, fcb, nullptr, out, N);
}

// Round 9
// 271.868 us; speedup vs baseline: 5.1587x; 1.0252x over previous
//
#include <hip/hip_runtime.h>

#define N_NODES 100000
#define IN_CH 64
#define HID 128
#define NBUCK ((N_NODES + 511) >> 9)   // 196 coarse buckets of 512 nodes
#define NCB 256                        // edge-chunk blocks for hist/bin

typedef short short8 __attribute__((ext_vector_type(8)));
typedef float floatx4 __attribute__((ext_vector_type(4)));
typedef float floatx2 __attribute__((ext_vector_type(2)));

__device__ __forceinline__ unsigned short f2bf(float f) {
    unsigned u = __builtin_bit_cast(unsigned, f);
    u += 0x7fffu + ((u >> 16) & 1u);  // RNE
    return (unsigned short)(u >> 16);
}

// acc += lo/hi bf16 half of packed pair p via VOP3P dot2.
__device__ __forceinline__ void dot2acc(float& acc, uint p, uint ones) {
    asm("v_dot2_f32_bf16 %0, %1, %2, %0" : "+v"(acc) : "v"(p), "v"(ones));
}
#define BF_ONE_LO 0x00003F80u
#define BF_ONE_HI 0x3F800000u

// ================= binned counting-sort CSR build (no global atomics) =================

__global__ __launch_bounds__(256) void hist_kernel(const int* __restrict__ dst,
                                                   int* __restrict__ table, int E, int chunk) {
    __shared__ int h[NBUCK];
    for (int i = threadIdx.x; i < NBUCK; i += 256) h[i] = 0;
    __syncthreads();
    int e0 = blockIdx.x * chunk;
    int e1 = min(E, e0 + chunk);
    for (int e = e0 + threadIdx.x; e < e1; e += 256) atomicAdd(&h[dst[e] >> 9], 1);
    __syncthreads();
    for (int i = threadIdx.x; i < NBUCK; i += 256) table[i * NCB + blockIdx.x] = h[i];
}

__global__ __launch_bounds__(256) void scanb1_kernel(int* __restrict__ table,
                                                     int* __restrict__ tot) {
    __shared__ int s[NCB];
    int b = blockIdx.x, t = threadIdx.x;
    int c = table[b * NCB + t];
    s[t] = c;
    __syncthreads();
#pragma unroll
    for (int off = 1; off < NCB; off <<= 1) {
        int v = (t >= off) ? s[t - off] : 0;
        __syncthreads();
        s[t] += v;
        __syncthreads();
    }
    table[b * NCB + t] = s[t] - c;
    if (t == NCB - 1) tot[b] = s[t];
}

__global__ __launch_bounds__(256) void scanb2_kernel(const int* __restrict__ tot,
                                                     int* __restrict__ bstart,
                                                     int* __restrict__ ptr, int E) {
    __shared__ int s[256];
    int t = threadIdx.x;
    int v = (t < NBUCK) ? tot[t] : 0;
    s[t] = v;
    __syncthreads();
#pragma unroll
    for (int off = 1; off < 256; off <<= 1) {
        int u = (t >= off) ? s[t - off] : 0;
        __syncthreads();
        s[t] += u;
        __syncthreads();
    }
    if (t < NBUCK) bstart[t] = s[t] - v;
    if (t == 0) {
        bstart[NBUCK] = E;
        ptr[N_NODES] = E;
    }
}

__global__ __launch_bounds__(256) void bin_kernel(const int* __restrict__ src,
                                                  const int* __restrict__ dst,
                                                  const int* __restrict__ table,
                                                  const int* __restrict__ bstart,
                                                  unsigned* __restrict__ binned, int E, int chunk) {
    __shared__ int cur[NBUCK];
    int blk = blockIdx.x;
    for (int i = threadIdx.x; i < NBUCK; i += 256) cur[i] = bstart[i] + table[i * NCB + blk];
    __syncthreads();
    int e0 = blk * chunk;
    int e1 = min(E, e0 + chunk);
    for (int e = e0 + threadIdx.x; e < e1; e += 256) {
        int d = dst[e];
        int b = d >> 9;
        int pos = atomicAdd(&cur[b], 1);  // LDS atomic
        binned[pos] = (unsigned)src[e] | ((unsigned)(d & 511) << 17);
    }
}

__global__ __launch_bounds__(256) void place_kernel(const unsigned* __restrict__ binned,
                                                    const int* __restrict__ bstart,
                                                    int* __restrict__ ptr,
                                                    int* __restrict__ sorted, int N) {
    __shared__ int deg[512];
    __shared__ int cur[512];
    __shared__ int ssum[256];
    int b = blockIdx.x, t = threadIdx.x;
    int start = bstart[b], end = bstart[b + 1];
    deg[t] = 0;
    deg[t + 256] = 0;
    __syncthreads();
    for (int i = start + t; i < end; i += 256) atomicAdd(&deg[binned[i] >> 17], 1);
    __syncthreads();
    int a = deg[2 * t], c = deg[2 * t + 1];
    int s2 = a + c;
    ssum[t] = s2;
    __syncthreads();
#pragma unroll
    for (int off = 1; off < 256; off <<= 1) {
        int u = (t >= off) ? ssum[t - off] : 0;
        __syncthreads();
        ssum[t] += u;
        __syncthreads();
    }
    int excl2 = ssum[t] - s2;
    cur[2 * t] = excl2;
    cur[2 * t + 1] = excl2 + a;
    int n0 = b * 512 + 2 * t;
    if (n0 < N) ptr[n0] = start + excl2;
    if (n0 + 1 < N) ptr[n0 + 1] = start + excl2 + a;
    __syncthreads();
    for (int i = start + t; i < end; i += 256) {
        unsigned p = binned[i];
        int dl = p >> 17;
        int pos = start + atomicAdd(&cur[dl], 1);  // LDS atomic
        sorted[pos] = (int)(p & 0x1FFFF);
    }
}

// ================= fused prep: bf16 convert of x + both weight packs =================
template <int K>
__device__ __forceinline__ void pack_dev(const float* __restrict__ Wn,
                                         const float* __restrict__ Ws,
                                         unsigned short* __restrict__ Bpack, int idx) {
    int s = idx >> 9;
    int rem = idx & 511;
    int t = rem >> 6;
    int lane = rem & 63;
    int quad = lane >> 4;
    int n = t * 16 + (lane & 15);
    unsigned short v[8];
#pragma unroll
    for (int j = 0; j < 8; ++j) {
        int k = s * 32 + quad * 8 + j;
        float w = (k < K) ? Wn[(size_t)k * HID + n] : Ws[(size_t)(k - K) * HID + n];
        v[j] = f2bf(w);
    }
    *(short8*)(Bpack + (size_t)idx * 8) = *(short8*)v;
}

__global__ __launch_bounds__(256) void prep_kernel(const float* __restrict__ x,
                                                   unsigned short* __restrict__ x_bf,
                                                   const float* __restrict__ Wn0,
                                                   const float* __restrict__ Ws0,
                                                   unsigned short* __restrict__ Bpack0,
                                                   const float* __restrict__ Wn1,
                                                   const float* __restrict__ Ws1,
                                                   unsigned short* __restrict__ Bpack1,
                                                   int n4) {
    int b = blockIdx.x;
    if (b < 8) {
        pack_dev<IN_CH>(Wn0, Ws0, Bpack0, b * 256 + threadIdx.x);
    } else if (b < 24) {
        pack_dev<HID>(Wn1, Ws1, Bpack1, (b - 8) * 256 + threadIdx.x);
    } else {
        int i = (b - 24) * 256 + threadIdx.x;
        if (i < n4) {
            float4 v = ((const float4*)x)[i];
            ushort4 o;
            o.x = f2bf(v.x); o.y = f2bf(v.y); o.z = f2bf(v.z); o.w = f2bf(v.w);
            ((ushort4*)x_bf)[i] = o;
        }
    }
}

// ================= gather + mean v5 (bf16 input, layer 0) =================
template <int C>
__global__ __launch_bounds__(256) void gather_mean(const int* __restrict__ ptr,
                                                   const int* __restrict__ srcs,
                                                   const unsigned short* __restrict__ feat,
                                                   unsigned short* __restrict__ mean, int N) {
    constexpr int LPR = C / 8;
    constexpr int G = 64 / LPR;
    constexpr int STEP = 4 * G;
    int w = (blockIdx.x * blockDim.x + threadIdx.x) >> 6;
    if (w >= N) return;
    int lane = threadIdx.x & 63;
    int g = lane / LPR;
    int l = lane % LPR;
    int s0 = ptr[w], s1 = ptr[w + 1];
    int deg = s1 - s0;

    float2 acc2[4];
#pragma unroll
    for (int u = 0; u < 4; ++u) acc2[u] = make_float2(0.0f, 0.0f);

    for (int jb = 0; jb < deg; jb += 64) {
        int rem = min(64, deg - jb);
        int idxreg = (jb + lane < deg) ? srcs[s0 + jb + lane] : 0;
        int fullend = rem & ~(STEP - 1);
        int o0 = 0;
        for (; o0 < fullend; o0 += STEP) {
            uint4 v[4];
#pragma unroll
            for (int q = 0; q < 4; ++q) {
                int idx = __shfl(idxreg, o0 + q * G + g);
                v[q] = *(const uint4*)(feat + (size_t)idx * C + l * 8);
            }
            const uint* p0 = (const uint*)&v[0];
            const uint* p1 = (const uint*)&v[1];
            const uint* p2 = (const uint*)&v[2];
            const uint* p3 = (const uint*)&v[3];
#pragma unroll
            for (int u = 0; u < 4; ++u) {
                dot2acc(acc2[u].x, p0[u], BF_ONE_LO); dot2acc(acc2[u].y, p0[u], BF_ONE_HI);
                dot2acc(acc2[u].x, p1[u], BF_ONE_LO); dot2acc(acc2[u].y, p1[u], BF_ONE_HI);
                dot2acc(acc2[u].x, p2[u], BF_ONE_LO); dot2acc(acc2[u].y, p2[u], BF_ONE_HI);
                dot2acc(acc2[u].x, p3[u], BF_ONE_LO); dot2acc(acc2[u].y, p3[u], BF_ONE_HI);
            }
        }
        if (o0 < rem) {
            uint4 v[4];
#pragma unroll
            for (int q = 0; q < 4; ++q) {
                int o = o0 + q * G + g;
                int idx = __shfl(idxreg, o);
                uint4 t = {0, 0, 0, 0};
                if (o < rem) t = *(const uint4*)(feat + (size_t)idx * C + l * 8);
                v[q] = t;
            }
            const uint* p0 = (const uint*)&v[0];
            const uint* p1 = (const uint*)&v[1];
            const uint* p2 = (const uint*)&v[2];
            const uint* p3 = (const uint*)&v[3];
#pragma unroll
            for (int u = 0; u < 4; ++u) {
                dot2acc(acc2[u].x, p0[u], BF_ONE_LO); dot2acc(acc2[u].y, p0[u], BF_ONE_HI);
                dot2acc(acc2[u].x, p1[u], BF_ONE_LO); dot2acc(acc2[u].y, p1[u], BF_ONE_HI);
                dot2acc(acc2[u].x, p2[u], BF_ONE_LO); dot2acc(acc2[u].y, p2[u], BF_ONE_HI);
                dot2acc(acc2[u].x, p3[u], BF_ONE_LO); dot2acc(acc2[u].y, p3[u], BF_ONE_HI);
            }
        }
    }
#pragma unroll
    for (int m = LPR; m < 64; m <<= 1) {
#pragma unroll
        for (int u = 0; u < 4; ++u) {
            acc2[u].x += __shfl_xor(acc2[u].x, m, 64);
            acc2[u].y += __shfl_xor(acc2[u].y, m, 64);
        }
    }
    if (g == 0) {
        float inv = (deg > 0) ? 1.0f / (float)deg : 0.0f;
        unsigned short o[8];
#pragma unroll
        for (int u = 0; u < 4; ++u) {
            o[2 * u + 0] = f2bf(acc2[u].x * inv);
            o[2 * u + 1] = f2bf(acc2[u].y * inv);
        }
        *(uint4*)(mean + (size_t)w * C + l * 8) = *(const uint4*)o;
    }
}

// ================= gather + mean fp8 (layer 1): 128ch rows of e4m3 =================
// 16 lanes/row x 8B (8 fp8 ch); G=4 slots, 4 in flight. HW v_cvt_pk_f32_fp8 decode.
__global__ __launch_bounds__(256) void gather_mean_f8(const int* __restrict__ ptr,
                                                      const int* __restrict__ srcs,
                                                      const unsigned char* __restrict__ feat,
                                                      unsigned short* __restrict__ mean, int N) {
    constexpr int C = HID;
    constexpr int LPR = 16;
    constexpr int G = 4;
    constexpr int STEP = 16;
    int w = (blockIdx.x * blockDim.x + threadIdx.x) >> 6;
    if (w >= N) return;
    int lane = threadIdx.x & 63;
    int g = lane / LPR;
    int l = lane % LPR;
    int s0 = ptr[w], s1 = ptr[w + 1];
    int deg = s1 - s0;

    floatx2 acc2[4];
#pragma unroll
    for (int u = 0; u < 4; ++u) { acc2[u][0] = 0.0f; acc2[u][1] = 0.0f; }

    for (int jb = 0; jb < deg; jb += 64) {
        int rem = min(64, deg - jb);
        int idxreg = (jb + lane < deg) ? srcs[s0 + jb + lane] : 0;
        int fullend = rem & ~(STEP - 1);
        int o0 = 0;
        for (; o0 < fullend; o0 += STEP) {
            uint2 v[4];
#pragma unroll
            for (int q = 0; q < 4; ++q) {
                int idx = __shfl(idxreg, o0 + q * G + g);
                v[q] = *(const uint2*)(feat + (size_t)idx * C + l * 8);
            }
#pragma unroll
            for (int q = 0; q < 4; ++q) {
                acc2[0] += __builtin_amdgcn_cvt_pk_f32_fp8(v[q].x, false);
                acc2[1] += __builtin_amdgcn_cvt_pk_f32_fp8(v[q].x, true);
                acc2[2] += __builtin_amdgcn_cvt_pk_f32_fp8(v[q].y, false);
                acc2[3] += __builtin_amdgcn_cvt_pk_f32_fp8(v[q].y, true);
            }
        }
        if (o0 < rem) {
            uint2 v[4];
#pragma unroll
            for (int q = 0; q < 4; ++q) {
                int o = o0 + q * G + g;
                int idx = __shfl(idxreg, o);
                uint2 t = {0, 0};
                if (o < rem) t = *(const uint2*)(feat + (size_t)idx * C + l * 8);
                v[q] = t;
            }
#pragma unroll
            for (int q = 0; q < 4; ++q) {
                acc2[0] += __builtin_amdgcn_cvt_pk_f32_fp8(v[q].x, false);
                acc2[1] += __builtin_amdgcn_cvt_pk_f32_fp8(v[q].x, true);
                acc2[2] += __builtin_amdgcn_cvt_pk_f32_fp8(v[q].y, false);
                acc2[3] += __builtin_amdgcn_cvt_pk_f32_fp8(v[q].y, true);
            }
        }
    }
#pragma unroll
    for (int m = LPR; m < 64; m <<= 1) {
#pragma unroll
        for (int u = 0; u < 4; ++u) {
            acc2[u][0] += __shfl_xor(acc2[u][0], m, 64);
            acc2[u][1] += __shfl_xor(acc2[u][1], m, 64);
        }
    }
    if (g == 0) {
        float inv = (deg > 0) ? 1.0f / (float)deg : 0.0f;
        unsigned short o[8];
#pragma unroll
        for (int u = 0; u < 4; ++u) {
            o[2 * u + 0] = f2bf(acc2[u][0] * inv);
            o[2 * u + 1] = f2bf(acc2[u][1] * inv);
        }
        *(uint4*)(mean + (size_t)w * C + l * 8) = *(const uint4*)o;
    }
}

// ================= MFMA SAGE GEMM: relu([mean|h] @ [Wn;Ws] + b) =================
// !FUSE_FC also emits an fp8(e4m3) copy of the output for the next aggregation.
template <int KT, bool FUSE_FC>
__global__ __launch_bounds__(256) void sage_gemm_mfma(const unsigned short* __restrict__ meanb,
                                                      const unsigned short* __restrict__ hb,
                                                      const unsigned short* __restrict__ Bpack,
                                                      const float* __restrict__ bias,
                                                      const float* __restrict__ fcw,
                                                      const float* __restrict__ fcb,
                                                      unsigned short* __restrict__ outb,
                                                      unsigned char* __restrict__ out8,
                                                      float* __restrict__ outf, int N) {
    constexpr int KH = KT / 2;
    constexpr int LDA = KT + 8;
    __shared__ unsigned short As[64 * LDA];
    const int t = threadIdx.x;
    const int row0 = blockIdx.x * 64;

    constexpr int SEGS = KT / 8;
    for (int c = t; c < 64 * SEGS; c += 256) {
        int r = c / SEGS, seg = c % SEGS;
        int rsrc = row0 + r;
        if (rsrc >= N) rsrc = N - 1;
        const unsigned short* srcp = (seg < SEGS / 2)
                                         ? meanb + (size_t)rsrc * KH + seg * 8
                                         : hb + (size_t)rsrc * KH + (seg - SEGS / 2) * 8;
        *(uint4*)&As[r * LDA + seg * 8] = *(const uint4*)srcp;
    }
    __syncthreads();

    const int lane = t & 63;
    const int wave = t >> 6;
    const int quad = lane >> 4;
    const int lo = lane & 15;

    floatx4 acc[8];
#pragma unroll
    for (int i = 0; i < 8; ++i)
#pragma unroll
        for (int r = 0; r < 4; ++r) acc[i][r] = 0.0f;

    const unsigned short* abase = &As[(wave * 16 + lo) * LDA + quad * 8];
#pragma unroll
    for (int s = 0; s < KT / 32; ++s) {
        short8 a = *(const short8*)(abase + s * 32);
        const short8* bp = (const short8*)Bpack + (size_t)(s * 8) * 64 + lane;
#pragma unroll
        for (int tt = 0; tt < 8; ++tt) {
            short8 b = bp[tt * 64];
            acc[tt] = __builtin_amdgcn_mfma_f32_16x16x32_bf16(a, b, acc[tt], 0, 0, 0);
        }
    }

    if (!FUSE_FC) {
#pragma unroll
        for (int tt = 0; tt < 8; ++tt) {
            int col = tt * 16 + lo;
            float bv = bias[col];
#pragma unroll
            for (int r = 0; r < 4; ++r) {
                int row = row0 + wave * 16 + quad * 4 + r;
                if (row < N) {
                    float v = fmaxf(acc[tt][r] + bv, 0.0f);
                    outb[(size_t)row * HID + col] = f2bf(v);
                    int p8 = __builtin_amdgcn_cvt_pk_fp8_f32(v, v, 0, false);
                    out8[(size_t)row * HID + col] = (unsigned char)(p8 & 0xff);
                }
            }
        }
    } else {
        float o0[4] = {}, o1[4] = {};
#pragma unroll
        for (int tt = 0; tt < 8; ++tt) {
            int col = tt * 16 + lo;
            float bv = bias[col];
            float w0 = fcw[col * 2 + 0];
            float w1 = fcw[col * 2 + 1];
#pragma unroll
            for (int r = 0; r < 4; ++r) {
                float v = fmaxf(acc[tt][r] + bv, 0.0f);
                o0[r] += v * w0;
                o1[r] += v * w1;
            }
        }
#pragma unroll
        for (int r = 0; r < 4; ++r) {
#pragma unroll
            for (int m = 8; m >= 1; m >>= 1) {
                o0[r] += __shfl_xor(o0[r], m, 16);
                o1[r] += __shfl_xor(o1[r], m, 16);
            }
        }
        if (lo == 0) {
#pragma unroll
            for (int r = 0; r < 4; ++r) {
                int row = row0 + wave * 16 + quad * 4 + r;
                if (row < N) {
                    outf[(size_t)row * 2 + 0] = o0[r] + fcb[0];
                    outf[(size_t)row * 2 + 1] = o1[r] + fcb[1];
                }
            }
        }
    }
}

extern "C" void kernel_launch(void* const* d_in, const int* in_sizes, int n_in,
                              void* d_out, int out_size, void* d_ws, size_t ws_size,
                              hipStream_t stream) {
    const float* x   = (const float*)d_in[0];
    const int*   ei  = (const int*)d_in[1];
    const float* Wn0 = (const float*)d_in[2];
    const float* Ws0 = (const float*)d_in[3];
    const float* b0  = (const float*)d_in[4];
    const float* Wn1 = (const float*)d_in[5];
    const float* Ws1 = (const float*)d_in[6];
    const float* b1  = (const float*)d_in[7];
    const float* fcw = (const float*)d_in[8];
    const float* fcb = (const float*)d_in[9];
    float* out = (float*)d_out;

    const int E = in_sizes[1] / 2;
    const int* src = ei;
    const int* dst = ei + E;
    const int N = N_NODES;
    const int chunk = (E + NCB - 1) / NCB;

    // workspace layout
    char* ws = (char*)d_ws;
    size_t off = 0;
    int* table  = (int*)(ws + off); off += (size_t)NBUCK * NCB * 4;
    int* tot    = (int*)(ws + off); off += 4096;
    int* bstart = (int*)(ws + off); off += 4096;
    int* ptr    = (int*)(ws + off); off += (size_t)(N + 1) * 4 + 60; off &= ~(size_t)63;
    unsigned* binned = (unsigned*)(ws + off); off += (size_t)E * 4;
    int* sorted = (int*)(ws + off); off += (size_t)E * 4;
    off = (off + 255) & ~(size_t)255;
    unsigned short* x_bf   = (unsigned short*)(ws + off); off += (size_t)N * IN_CH * 2;
    unsigned short* mean0  = (unsigned short*)(ws + off); off += (size_t)N * IN_CH * 2;
    unsigned short* h1_bf  = (unsigned short*)(ws + off); off += (size_t)N * HID * 2;
    unsigned short* mean1  = (unsigned short*)(ws + off); off += (size_t)N * HID * 2;
    unsigned char*  h1_f8  = (unsigned char*)(ws + off);  off += (size_t)N * HID;
    off = (off + 255) & ~(size_t)255;
    unsigned short* Bpack0 = (unsigned short*)(ws + off); off += (size_t)(2 * IN_CH / 32) * 8 * 64 * 8 * 2;
    unsigned short* Bpack1 = (unsigned short*)(ws + off); off += (size_t)(2 * HID / 32) * 8 * 64 * 8 * 2;

    // ---- CSR build (binned counting sort, zero global atomics) ----
    hist_kernel<<<NCB, 256, 0, stream>>>(dst, table, E, chunk);
    scanb1_kernel<<<NBUCK, 256, 0, stream>>>(table, tot);
    scanb2_kernel<<<1, 256, 0, stream>>>(tot, bstart, ptr, E);
    bin_kernel<<<NCB, 256, 0, stream>>>(src, dst, table, bstart, binned, E, chunk);
    place_kernel<<<NBUCK, 256, 0, stream>>>(binned, bstart, ptr, sorted, N);

    // ---- fused conversions / weight packing ----
    {
        int n4 = N * IN_CH / 4;
        prep_kernel<<<24 + (n4 + 255) / 256, 256, 0, stream>>>(x, x_bf, Wn0, Ws0, Bpack0,
                                                               Wn1, Ws1, Bpack1, n4);
    }

    // ---- layer 0 ----
    gather_mean<IN_CH><<<(N * 64 + 255) / 256, 256, 0, stream>>>(ptr, sorted, x_bf, mean0, N);
    sage_gemm_mfma<2 * IN_CH, false><<<(N + 63) / 64, 256, 0, stream>>>(
        mean0, x_bf, Bpack0, b0, nullptr, nullptr, h1_bf, h1_f8, nullptr, N);

    // ---- layer 1 (fp8 aggregation) + fused fc ----
    gather_mean_f8<<<(N * 64 + 255) / 256, 256, 0, stream>>>(ptr, sorted, h1_f8, mean1, N);
    sage_gemm_mfma<2 * HID, true><<<(N + 63) / 64, 256, 0, stream>>>(
        mean1, h1_bf, Bpack1, b1, fcw, fcb, nullptr, nullptr, out, N);
}